// Round 1
// baseline (1438.592 us; speedup 1.0000x reference)
//
#include <hip/hip_runtime.h>
#include <hip/hip_bf16.h>
#include <cstddef>

#define C_ 32
#define D_ 48
#define H_ 64
#define W_ 208
#define HW_ (H_*W_)          // 13312
#define EPS_ 1e-5f

typedef __attribute__((ext_vector_type(8))) short short8;
typedef __attribute__((ext_vector_type(4))) float float4v;

// ---------------------------------------------------------------------------
// Prep: L1-normalize guidance weights; repack conv weights into MFMA A-frag
// layout wrep[ch][tap][lane][j] with co = ch*16 + (lane&15), ci = (lane>>4)*8+j
// ---------------------------------------------------------------------------
__global__ __launch_bounds__(256) void prep_kernel(
    const float* __restrict__ g, const float* __restrict__ cw,
    float* __restrict__ wn, __hip_bfloat16* __restrict__ wrep)
{
    int idx = blockIdx.x * 256 + threadIdx.x;
    if (idx < 4 * HW_) {
        int dir = idx / HW_;
        int hw  = idx % HW_;
        const float* gb = g + dir * 5 * HW_ + hw;
        float v0 = gb[0*HW_], v1 = gb[1*HW_], v2 = gb[2*HW_], v3 = gb[3*HW_], v4 = gb[4*HW_];
        float s = fabsf(v0)+fabsf(v1)+fabsf(v2)+fabsf(v3)+fabsf(v4);
        float inv = 1.0f / fmaxf(s, 1e-12f);
        float* ob = wn + dir * 5 * HW_ + hw;
        ob[0*HW_] = v0*inv; ob[1*HW_] = v1*inv; ob[2*HW_] = v2*inv;
        ob[3*HW_] = v3*inv; ob[4*HW_] = v4*inv;
    } else {
        int j = idx - 4 * HW_;
        if (j < 2 * 27 * 64 * 8) {
            int e    = j & 7;
            int lane = (j >> 3) & 63;
            int tap  = (j >> 9) % 27;
            int ch   = j / (512 * 27);
            int co = ch * 16 + (lane & 15);
            int ci = (lane >> 4) * 8 + e;
            wrep[j] = __float2bfloat16(cw[(co * C_ + ci) * 27 + tap]);
        }
    }
}

// ---------------------------------------------------------------------------
// One SGA recurrence step. Lane d holds A[d]; weights are wave-uniform
// (w5 points at weight i=0 for this scan position, stride HW_ between i).
// ---------------------------------------------------------------------------
__device__ __forceinline__ float sga_step(float A, float xi,
                                          const float* __restrict__ w5,
                                          bool actv, int lane)
{
    float w0 = w5[0*HW_], w1 = w5[1*HW_], w2 = w5[2*HW_], w3 = w5[3*HW_], w4 = w5[4*HW_];
    float up = __shfl(A, lane == 0 ? 0 : lane - 1, 64);     // A[d-1], clamp at 0
    float dn = __shfl(A, lane >= 47 ? 47 : lane + 1, 64);   // A[d+1], clamp at 47
    float m = actv ? A : -3.4e38f;
    #pragma unroll
    for (int off = 1; off < 64; off <<= 1)
        m = fmaxf(m, __shfl_xor(m, off, 64));
    return w0*xi + w1*A + w2*up + w3*dn + w4*m;
}

// ---------------------------------------------------------------------------
// Kernel 3: horizontal scans (dir1 L->R, dir2 R->L). Row = (c,h), lane = d.
// Writes max(d1,d2) into d12 (= d_out used as fp32 scratch).
// ---------------------------------------------------------------------------
__global__ __launch_bounds__(256) void sga_w_kernel(
    const float* __restrict__ x, const float* __restrict__ wn,
    float* __restrict__ d12)
{
    int lane = threadIdx.x & 63;
    int wid  = blockIdx.x * 4 + (threadIdx.x >> 6);   // 0..2047
    int c = wid >> 6;
    int h = wid & 63;
    int d = lane < 48 ? lane : 47;
    bool actv = lane < 48;

    const float* px  = x   + ((size_t)(c*D_ + d)*H_ + h) * W_;
    float*       po  = d12 + ((size_t)(c*D_ + d)*H_ + h) * W_;
    const float* w1b = wn + 0 * 5 * HW_ + h * W_;
    const float* w2b = wn + 1 * 5 * HW_ + h * W_;

    // dir 1: left -> right (carry init = x[0])
    float A = px[0];
    for (int p = 0; p < W_; ++p) {
        A = sga_step(A, px[p], w1b + p, actv, lane);
        if (actv) po[p] = A;
    }
    // dir 2: right -> left (carry init = x[W-1])
    A = px[W_ - 1];
    for (int p = W_ - 1; p >= 0; --p) {
        A = sga_step(A, px[p], w2b + p, actv, lane);
        if (actv) po[p] = fmaxf(po[p], A);
    }
}

// ---------------------------------------------------------------------------
// Kernel 4: vertical scans (dir3 T->B staged in LDS, dir4 B->T), combine all
// 4 directions, fuse BN1+ReLU, emit bf16 act in [H][D][W][C] layout.
// Row = (c,w), lane = d.
// ---------------------------------------------------------------------------
__global__ __launch_bounds__(256) void sga_h_kernel(
    const float* __restrict__ x, const float* __restrict__ wn,
    const float* __restrict__ d12,
    const float* __restrict__ g1, const float* __restrict__ b1,
    const float* __restrict__ m1, const float* __restrict__ v1,
    __hip_bfloat16* __restrict__ act)
{
    __shared__ float lds[4 * H_ * D_];   // 4 waves * 64*48 * 4B = 48 KiB
    int lane = threadIdx.x & 63;
    int wid  = blockIdx.x * 4 + (threadIdx.x >> 6);   // 0..6655
    int c = wid / W_;
    int w = wid % W_;
    int d = lane < 48 ? lane : 47;
    bool actv = lane < 48;
    float* ldsw = lds + (threadIdx.x >> 6) * (H_ * D_);

    const float* px  = x   + (size_t)(c*D_ + d) * HW_ + w;   // step p: px[p*W_]
    const float* pdb = d12 + (size_t)(c*D_ + d) * HW_ + w;
    const float* w3b = wn + 2 * 5 * HW_ + w;                 // + p*W_
    const float* w4b = wn + 3 * 5 * HW_ + w;

    // dir 3: top -> bottom, stage into LDS
    float A = px[0];
    for (int p = 0; p < H_; ++p) {
        A = sga_step(A, px[p * W_], w3b + p * W_, actv, lane);
        if (actv) ldsw[p * D_ + d] = A;
    }
    // dir 4: bottom -> top, combine + BN1 + ReLU + bf16 store
    float s1 = g1[c] * rsqrtf(v1[c] + EPS_);
    float o1 = b1[c] - m1[c] * s1;
    A = px[(H_ - 1) * W_];
    for (int p = H_ - 1; p >= 0; --p) {
        A = sga_step(A, px[p * W_], w4b + p * W_, actv, lane);
        if (actv) {
            float comb = fmaxf(ldsw[p * D_ + d], A);
            comb = fmaxf(comb, pdb[p * W_]);
            float v = fmaxf(comb * s1 + o1, 0.0f);
            act[((size_t)(p * D_ + d) * W_ + w) * C_ + c] = __float2bfloat16(v);
        }
    }
}

// ---------------------------------------------------------------------------
// Conv 3x3x3 (C=32->32) as implicit GEMM on MFMA 16x16x32 bf16.
// One wave computes out tile [16 co][16 w] for fixed (d,h); K = 32 ci per tap.
// Epilogue fuses BN2 + residual + ReLU.
// ---------------------------------------------------------------------------
__global__ __launch_bounds__(256) void conv_kernel(
    const __hip_bfloat16* __restrict__ act,   // [H][D][W][C]
    const short8* __restrict__ wrep,          // [2][27][64] short8
    const float* __restrict__ x,
    const float* __restrict__ g2, const float* __restrict__ b2,
    const float* __restrict__ m2, const float* __restrict__ v2,
    float* __restrict__ out)
{
    int lane = threadIdx.x & 63;
    int wid  = blockIdx.x * 4 + (threadIdx.x >> 6);   // 0..79871
    int ch = wid & 1;
    int t1 = wid >> 1;
    int wt = t1 % 13;
    int t2 = t1 / 13;
    int d  = t2 % 48;
    int h  = t2 / 48;
    int w0 = wt * 16;
    int n   = lane & 15;
    int ci0 = (lane >> 4) * 8;

    float4v acc = {0.f, 0.f, 0.f, 0.f};
    const short8* wbase = wrep + (size_t)(ch * 27) * 64 + lane;

    #pragma unroll
    for (int kd = 0; kd < 3; ++kd) {
        int dd = d + kd - 1;
        if (dd < 0 || dd >= D_) continue;
        #pragma unroll
        for (int kh = 0; kh < 3; ++kh) {
            int hh = h + kh - 1;
            if (hh < 0 || hh >= H_) continue;
            const __hip_bfloat16* abase = act + ((size_t)(hh * D_ + dd) * W_) * C_;
            #pragma unroll
            for (int kw = 0; kw < 3; ++kw) {
                int ww = w0 + kw - 1 + n;
                int tap = (kd * 3 + kh) * 3 + kw;
                short8 bfrag = {0,0,0,0,0,0,0,0};
                if (ww >= 0 && ww < W_)
                    bfrag = *(const short8*)(abase + (size_t)ww * C_ + ci0);
                short8 afrag = wbase[tap * 64];
                acc = __builtin_amdgcn_mfma_f32_16x16x32_bf16(afrag, bfrag, acc, 0, 0, 0);
            }
        }
    }

    int cobase = ch * 16 + (lane >> 4) * 4;
    int wl = w0 + n;
    #pragma unroll
    for (int r = 0; r < 4; ++r) {
        int co = cobase + r;
        float s2 = g2[co] * rsqrtf(v2[co] + EPS_);
        float o2 = b2[co] - m2[co] * s2;
        size_t idx = ((size_t)(co * D_ + d) * H_ + h) * W_ + wl;
        out[idx] = fmaxf(acc[r] * s2 + o2 + x[idx], 0.0f);
    }
}

// ---------------------------------------------------------------------------
extern "C" void kernel_launch(void* const* d_in, const int* in_sizes, int n_in,
                              void* d_out, int out_size, void* d_ws, size_t ws_size,
                              hipStream_t stream)
{
    const float* x    = (const float*)d_in[0];
    const float* g    = (const float*)d_in[1];
    const float* cw   = (const float*)d_in[2];
    const float* bn1g = (const float*)d_in[3];
    const float* bn1b = (const float*)d_in[4];
    const float* bn1m = (const float*)d_in[5];
    const float* bn1v = (const float*)d_in[6];
    const float* bn2g = (const float*)d_in[7];
    const float* bn2b = (const float*)d_in[8];
    const float* bn2m = (const float*)d_in[9];
    const float* bn2v = (const float*)d_in[10];
    float* out = (float*)d_out;

    char* ws = (char*)d_ws;
    float* wn = (float*)ws;                                        // 4*5*13312 f = 1,064,960 B
    __hip_bfloat16* wrep = (__hip_bfloat16*)(ws + 1064960);        // 27648 bf16 = 55,296 B
    __hip_bfloat16* act  = (__hip_bfloat16*)(ws + 1064960 + 55296);// 20,447,232 bf16 = 40.9 MB

    // 1) normalize guidance + repack conv weights
    prep_kernel<<<316, 256, 0, stream>>>(g, cw, wn, wrep);
    // 2) horizontal scans -> max(d1,d2) into d_out (fp32 scratch)
    sga_w_kernel<<<512, 256, 0, stream>>>(x, wn, out);
    // 3) vertical scans + combine + BN1 + ReLU -> bf16 act [H][D][W][C]
    sga_h_kernel<<<1664, 256, 0, stream>>>(x, wn, out, bn1g, bn1b, bn1m, bn1v, act);
    // 4) conv 3x3x3 (MFMA) + BN2 + residual + ReLU -> d_out
    conv_kernel<<<19968, 256, 0, stream>>>(act, (const short8*)wrep, x,
                                           bn2g, bn2b, bn2m, bn2v, out);
}

// Round 2
// 912.212 us; speedup vs baseline: 1.5770x; 1.5770x over previous
//
#include <hip/hip_runtime.h>
#include <hip/hip_bf16.h>
#include <cstddef>

#define C_ 32
#define D_ 48
#define H_ 64
#define W_ 208
#define HW_ (H_*W_)          // 13312
#define EPS_ 1e-5f

typedef __attribute__((ext_vector_type(8))) short short8;
typedef __attribute__((ext_vector_type(4))) float float4v;

// ---------------------------------------------------------------------------
// Prep: L1-normalize guidance weights; repack conv weights into MFMA A-frag
// layout wrep[ch][tap][lane][j] with co = ch*16 + (lane&15), ci = (lane>>4)*8+j
// ---------------------------------------------------------------------------
__global__ __launch_bounds__(256) void prep_kernel(
    const float* __restrict__ g, const float* __restrict__ cw,
    float* __restrict__ wn, __hip_bfloat16* __restrict__ wrep)
{
    int idx = blockIdx.x * 256 + threadIdx.x;
    if (idx < 4 * HW_) {
        int dir = idx / HW_;
        int hw  = idx % HW_;
        const float* gb = g + dir * 5 * HW_ + hw;
        float v0 = gb[0*HW_], v1 = gb[1*HW_], v2 = gb[2*HW_], v3 = gb[3*HW_], v4 = gb[4*HW_];
        float s = fabsf(v0)+fabsf(v1)+fabsf(v2)+fabsf(v3)+fabsf(v4);
        float inv = 1.0f / fmaxf(s, 1e-12f);
        float* ob = wn + dir * 5 * HW_ + hw;
        ob[0*HW_] = v0*inv; ob[1*HW_] = v1*inv; ob[2*HW_] = v2*inv;
        ob[3*HW_] = v3*inv; ob[4*HW_] = v4*inv;
    } else {
        int j = idx - 4 * HW_;
        if (j < 2 * 27 * 64 * 8) {
            int e    = j & 7;
            int lane = (j >> 3) & 63;
            int tap  = (j >> 9) % 27;
            int ch   = j / (512 * 27);
            int co = ch * 16 + (lane & 15);
            int ci = (lane >> 4) * 8 + e;
            wrep[j] = __float2bfloat16(cw[(co * C_ + ci) * 27 + tap]);
        }
    }
}

// ---------------------------------------------------------------------------
// One SGA recurrence step. Lane d holds A[d]; weights are wave-uniform values.
// ---------------------------------------------------------------------------
__device__ __forceinline__ float sga_step2(float A, float xi,
    float w0, float w1, float w2, float w3, float w4, bool actv, int lane)
{
    float up = __shfl(A, lane == 0 ? 0 : lane - 1, 64);     // A[d-1], clamp at 0
    float dn = __shfl(A, lane >= 47 ? 47 : lane + 1, 64);   // A[d+1], clamp at 47
    float m = actv ? A : -3.4e38f;
    #pragma unroll
    for (int off = 1; off < 64; off <<= 1)
        m = fmaxf(m, __shfl_xor(m, off, 64));
    return w0*xi + w1*A + w2*up + w3*dn + w4*m;
}

// ---------------------------------------------------------------------------
// Kernel: horizontal scans (dir1 L->R, dir2 R->L), LDS-staged tiles.
// Block = 4 waves = 4 h rows (same c). Writes max(d1,d2) into d12 (d_out).
// ---------------------------------------------------------------------------
__global__ __launch_bounds__(256) void sga_w_kernel(
    const float* __restrict__ x, const float* __restrict__ wn,
    float* __restrict__ d12)
{
    __shared__ float xbuf[48 * 257];     // [d][4h*64w], row stride 257 (pad)
    __shared__ float wbuf[4 * 5 * 64];   // [hi][i][p]
    int tid  = threadIdx.x;
    int lane = tid & 63;
    int hi   = tid >> 6;                 // wave index = h sub-row
    int c    = blockIdx.x >> 4;
    int h0   = (blockIdx.x & 15) * 4;
    int d    = lane < 48 ? lane : 47;
    bool actv = lane < 48;

    float A = 0.0f;
    // ---- dir 1: left -> right ----
    for (int ch = 0; ch < 4; ++ch) {
        int p0 = ch * 64, len = (ch == 3) ? 16 : 64;
        #pragma unroll
        for (int k = 0; k < 48; ++k) {
            int f = tid + 256 * k;
            int p = f & 63, hj = (f >> 6) & 3, dd = f >> 8;
            if (p < len)
                xbuf[dd * 257 + hj * 64 + p] =
                    x[((size_t)(c * 48 + dd) * 64 + h0 + hj) * 208 + p0 + p];
        }
        #pragma unroll
        for (int k = 0; k < 5; ++k) {
            int f = tid + 256 * k;
            int p = f & 63, i = (f >> 6) % 5, hj = f / 320;
            if (p < len)
                wbuf[hj * 320 + i * 64 + p] =
                    wn[(size_t)0 * 5 * HW_ + (size_t)i * HW_ + (h0 + hj) * 208 + p0 + p];
        }
        __syncthreads();
        float* xb = xbuf + d * 257 + hi * 64;
        const float* wb = wbuf + hi * 320;
        if (ch == 0) A = xb[0];
        #pragma unroll 4
        for (int p = 0; p < len; ++p) {
            float xi = xb[p];
            A = sga_step2(A, xi, wb[p], wb[64+p], wb[128+p], wb[192+p], wb[256+p], actv, lane);
            if (actv) xb[p] = A;
        }
        __syncthreads();
        #pragma unroll
        for (int k = 0; k < 48; ++k) {
            int f = tid + 256 * k;
            int p = f & 63, hj = (f >> 6) & 3, dd = f >> 8;
            if (p < len)
                d12[((size_t)(c * 48 + dd) * 64 + h0 + hj) * 208 + p0 + p] =
                    xbuf[dd * 257 + hj * 64 + p];
        }
        __syncthreads();
    }
    // ---- dir 2: right -> left ----
    for (int ch = 3; ch >= 0; --ch) {
        int p0 = ch * 64, len = (ch == 3) ? 16 : 64;
        #pragma unroll
        for (int k = 0; k < 48; ++k) {
            int f = tid + 256 * k;
            int p = f & 63, hj = (f >> 6) & 3, dd = f >> 8;
            if (p < len)
                xbuf[dd * 257 + hj * 64 + p] =
                    x[((size_t)(c * 48 + dd) * 64 + h0 + hj) * 208 + p0 + p];
        }
        #pragma unroll
        for (int k = 0; k < 5; ++k) {
            int f = tid + 256 * k;
            int p = f & 63, i = (f >> 6) % 5, hj = f / 320;
            if (p < len)
                wbuf[hj * 320 + i * 64 + p] =
                    wn[(size_t)1 * 5 * HW_ + (size_t)i * HW_ + (h0 + hj) * 208 + p0 + p];
        }
        __syncthreads();
        float* xb = xbuf + d * 257 + hi * 64;
        const float* wb = wbuf + hi * 320;
        if (ch == 3) A = xb[len - 1];
        #pragma unroll 4
        for (int p = len - 1; p >= 0; --p) {
            float xi = xb[p];
            A = sga_step2(A, xi, wb[p], wb[64+p], wb[128+p], wb[192+p], wb[256+p], actv, lane);
            if (actv) xb[p] = A;
        }
        __syncthreads();
        #pragma unroll
        for (int k = 0; k < 48; ++k) {
            int f = tid + 256 * k;
            int p = f & 63, hj = (f >> 6) & 3, dd = f >> 8;
            if (p < len) {
                size_t gi = ((size_t)(c * 48 + dd) * 64 + h0 + hj) * 208 + p0 + p;
                d12[gi] = fmaxf(d12[gi], xbuf[dd * 257 + hj * 64 + p]);
            }
        }
        __syncthreads();
    }
}

// ---------------------------------------------------------------------------
// Kernel: vertical scans (dir3 T->B in registers, dir4 B->T), combine with
// d12, fuse BN1+ReLU, write fp32 result IN PLACE into d12 (x-layout).
// Block = 8 waves = 8 w columns (same c). 16-h chunks staged in LDS.
// ---------------------------------------------------------------------------
__global__ __launch_bounds__(512) void sga_h_kernel(
    const float* __restrict__ x, const float* __restrict__ wn,
    float* __restrict__ d12,
    const float* __restrict__ g1, const float* __restrict__ b1,
    const float* __restrict__ m1, const float* __restrict__ v1)
{
    __shared__ float xbuf[48 * 129];     // [d][hh*8+wi], row stride 129 (pad)
    __shared__ float wbuf[5 * 16 * 8];   // [i][hh][wi]
    int tid  = threadIdx.x;
    int lane = tid & 63;
    int wi   = tid >> 6;                 // wave index = w sub-column (0..7)
    int c    = blockIdx.x / 26;
    int w0   = (blockIdx.x % 26) * 8;
    int d    = lane < 48 ? lane : 47;
    bool actv = lane < 48;

    float s1 = g1[c] * rsqrtf(v1[c] + EPS_);
    float o1 = b1[c] - m1[c] * s1;

    float d3[64];
    float A = 0.0f;
    // ---- dir 3: top -> bottom (results in registers) ----
    #pragma unroll
    for (int ch = 0; ch < 4; ++ch) {
        int h0 = ch * 16;
        #pragma unroll
        for (int k = 0; k < 12; ++k) {
            int f = tid + 512 * k;
            int wl = f & 7, hh = (f >> 3) & 15, dd = f >> 7;
            xbuf[dd * 129 + hh * 8 + wl] =
                x[((size_t)(c * 48 + dd) * 64 + h0 + hh) * 208 + w0 + wl];
        }
        #pragma unroll
        for (int k = 0; k < 2; ++k) {
            int f = tid + 512 * k;
            if (f < 640) {
                int wl = f & 7, hh = (f >> 3) & 15, i = f >> 7;
                wbuf[i * 128 + hh * 8 + wl] =
                    wn[(size_t)2 * 5 * HW_ + (size_t)i * HW_ + (h0 + hh) * 208 + w0 + wl];
            }
        }
        __syncthreads();
        float* xb = xbuf + d * 129 + wi;
        if (ch == 0) A = xb[0];
        #pragma unroll
        for (int hh = 0; hh < 16; ++hh) {
            float xi = xb[hh * 8];
            A = sga_step2(A, xi, wbuf[hh*8+wi], wbuf[128+hh*8+wi], wbuf[256+hh*8+wi],
                          wbuf[384+hh*8+wi], wbuf[512+hh*8+wi], actv, lane);
            d3[ch * 16 + hh] = A;
        }
        __syncthreads();
    }
    // ---- dir 4: bottom -> top, combine + BN1 + ReLU, in-place into d12 ----
    #pragma unroll
    for (int ch = 3; ch >= 0; --ch) {
        int h0 = ch * 16;
        #pragma unroll
        for (int k = 0; k < 12; ++k) {
            int f = tid + 512 * k;
            int wl = f & 7, hh = (f >> 3) & 15, dd = f >> 7;
            xbuf[dd * 129 + hh * 8 + wl] =
                x[((size_t)(c * 48 + dd) * 64 + h0 + hh) * 208 + w0 + wl];
        }
        #pragma unroll
        for (int k = 0; k < 2; ++k) {
            int f = tid + 512 * k;
            if (f < 640) {
                int wl = f & 7, hh = (f >> 3) & 15, i = f >> 7;
                wbuf[i * 128 + hh * 8 + wl] =
                    wn[(size_t)3 * 5 * HW_ + (size_t)i * HW_ + (h0 + hh) * 208 + w0 + wl];
            }
        }
        __syncthreads();
        float* xb = xbuf + d * 129 + wi;
        if (ch == 3) A = xb[15 * 8];
        #pragma unroll
        for (int hh = 15; hh >= 0; --hh) {
            float xi = xb[hh * 8];
            A = sga_step2(A, xi, wbuf[hh*8+wi], wbuf[128+hh*8+wi], wbuf[256+hh*8+wi],
                          wbuf[384+hh*8+wi], wbuf[512+hh*8+wi], actv, lane);
            if (actv) xb[hh * 8] = fmaxf(d3[ch * 16 + hh], A);   // comb(d3,d4) in place
        }
        __syncthreads();
        #pragma unroll
        for (int k = 0; k < 12; ++k) {
            int f = tid + 512 * k;
            int wl = f & 7, hh = (f >> 3) & 15, dd = f >> 7;
            size_t gi = ((size_t)(c * 48 + dd) * 64 + h0 + hh) * 208 + w0 + wl;
            float v = fmaxf(xbuf[dd * 129 + hh * 8 + wl], d12[gi]);
            d12[gi] = fmaxf(v * s1 + o1, 0.0f);
        }
        __syncthreads();
    }
}

// ---------------------------------------------------------------------------
// Transpose: s fp32 [C][D][H][W] (in d_out) -> act bf16 [H][D][W][C] (in ws).
// One block per (d,h): tile [32 c][208 w].
// ---------------------------------------------------------------------------
__global__ __launch_bounds__(256) void trans_kernel(
    const float* __restrict__ s, __hip_bfloat16* __restrict__ act)
{
    __shared__ float t[32 * 209];
    int tid = threadIdx.x;
    int d = blockIdx.x % 48;
    int h = blockIdx.x / 48;
    #pragma unroll
    for (int k = 0; k < 26; ++k) {
        int f = tid + 256 * k;           // f < 6656
        int wl = f % 208, ci = f / 208;
        t[ci * 209 + wl] = s[((size_t)(ci * 48 + d) * 64 + h) * 208 + wl];
    }
    __syncthreads();
    unsigned* actu = (unsigned*)act;
    #pragma unroll
    for (int k = 0; k < 13; ++k) {
        int f = tid + 256 * k;           // f < 3328
        int cp = f & 15, wl = f >> 4;
        union { unsigned u; __hip_bfloat16 hh[2]; } pk;
        pk.hh[0] = __float2bfloat16(t[(2 * cp) * 209 + wl]);
        pk.hh[1] = __float2bfloat16(t[(2 * cp + 1) * 209 + wl]);
        actu[((size_t)(h * 48 + d) * 208 + wl) * 16 + cp] = pk.u;
    }
}

// ---------------------------------------------------------------------------
// Conv 3x3x3 (C=32->32) as implicit GEMM on MFMA 16x16x32 bf16.
// One wave computes out tile [16 co][16 w] for fixed (d,h); K = 32 ci per tap.
// Epilogue fuses BN2 + residual + ReLU.
// ---------------------------------------------------------------------------
__global__ __launch_bounds__(256) void conv_kernel(
    const __hip_bfloat16* __restrict__ act,   // [H][D][W][C]
    const short8* __restrict__ wrep,          // [2][27][64] short8
    const float* __restrict__ x,
    const float* __restrict__ g2, const float* __restrict__ b2,
    const float* __restrict__ m2, const float* __restrict__ v2,
    float* __restrict__ out)
{
    int lane = threadIdx.x & 63;
    int wid  = blockIdx.x * 4 + (threadIdx.x >> 6);   // 0..79871
    int ch = wid & 1;
    int t1 = wid >> 1;
    int wt = t1 % 13;
    int t2 = t1 / 13;
    int d  = t2 % 48;
    int h  = t2 / 48;
    int w0 = wt * 16;
    int n   = lane & 15;
    int ci0 = (lane >> 4) * 8;

    float4v acc = {0.f, 0.f, 0.f, 0.f};
    const short8* wbase = wrep + (size_t)(ch * 27) * 64 + lane;

    #pragma unroll
    for (int kd = 0; kd < 3; ++kd) {
        int dd = d + kd - 1;
        if (dd < 0 || dd >= D_) continue;
        #pragma unroll
        for (int kh = 0; kh < 3; ++kh) {
            int hh = h + kh - 1;
            if (hh < 0 || hh >= H_) continue;
            const __hip_bfloat16* abase = act + ((size_t)(hh * D_ + dd) * W_) * C_;
            #pragma unroll
            for (int kw = 0; kw < 3; ++kw) {
                int ww = w0 + kw - 1 + n;
                int tap = (kd * 3 + kh) * 3 + kw;
                short8 bfrag = {0,0,0,0,0,0,0,0};
                if (ww >= 0 && ww < W_)
                    bfrag = *(const short8*)(abase + (size_t)ww * C_ + ci0);
                short8 afrag = wbase[tap * 64];
                acc = __builtin_amdgcn_mfma_f32_16x16x32_bf16(afrag, bfrag, acc, 0, 0, 0);
            }
        }
    }

    int cobase = ch * 16 + (lane >> 4) * 4;
    int wl = w0 + n;
    #pragma unroll
    for (int r = 0; r < 4; ++r) {
        int co = cobase + r;
        float s2 = g2[co] * rsqrtf(v2[co] + EPS_);
        float o2 = b2[co] - m2[co] * s2;
        size_t idx = ((size_t)(co * D_ + d) * H_ + h) * W_ + wl;
        out[idx] = fmaxf(acc[r] * s2 + o2 + x[idx], 0.0f);
    }
}

// ---------------------------------------------------------------------------
extern "C" void kernel_launch(void* const* d_in, const int* in_sizes, int n_in,
                              void* d_out, int out_size, void* d_ws, size_t ws_size,
                              hipStream_t stream)
{
    const float* x    = (const float*)d_in[0];
    const float* g    = (const float*)d_in[1];
    const float* cw   = (const float*)d_in[2];
    const float* bn1g = (const float*)d_in[3];
    const float* bn1b = (const float*)d_in[4];
    const float* bn1m = (const float*)d_in[5];
    const float* bn1v = (const float*)d_in[6];
    const float* bn2g = (const float*)d_in[7];
    const float* bn2b = (const float*)d_in[8];
    const float* bn2m = (const float*)d_in[9];
    const float* bn2v = (const float*)d_in[10];
    float* out = (float*)d_out;

    char* ws = (char*)d_ws;
    float* wn = (float*)ws;                                        // 1,064,960 B
    __hip_bfloat16* wrep = (__hip_bfloat16*)(ws + 1064960);        // 55,296 B
    __hip_bfloat16* act  = (__hip_bfloat16*)(ws + 1064960 + 55296);// 40.9 MB

    // 1) normalize guidance + repack conv weights
    prep_kernel<<<316, 256, 0, stream>>>(g, cw, wn, wrep);
    // 2) horizontal scans -> max(d1,d2) into d_out (fp32 scratch)
    sga_w_kernel<<<512, 256, 0, stream>>>(x, wn, out);
    // 3) vertical scans + combine + BN1 + ReLU -> fp32, in place in d_out
    sga_h_kernel<<<832, 512, 0, stream>>>(x, wn, out, bn1g, bn1b, bn1m, bn1v);
    // 4) transpose to bf16 act [H][D][W][C]
    trans_kernel<<<3072, 256, 0, stream>>>(out, act);
    // 5) conv 3x3x3 (MFMA) + BN2 + residual + ReLU -> d_out
    conv_kernel<<<19968, 256, 0, stream>>>(act, (const short8*)wrep, x,
                                           bn2g, bn2b, bn2m, bn2v, out);
}

// Round 3
// 758.381 us; speedup vs baseline: 1.8969x; 1.2028x over previous
//
#include <hip/hip_runtime.h>
#include <hip/hip_bf16.h>
#include <cstddef>

#define C_ 32
#define D_ 48
#define H_ 64
#define W_ 208
#define HW_ (H_*W_)          // 13312
#define EPS_ 1e-5f

typedef __attribute__((ext_vector_type(8))) short short8;
typedef __attribute__((ext_vector_type(4))) float float4v;

// ---------------------------------------------------------------------------
// DPP helpers (VALU-latency cross-lane; invalid lanes keep old = src)
// ---------------------------------------------------------------------------
template<int CTRL>
__device__ __forceinline__ float dppmov(float x) {
    int v = __builtin_bit_cast(int, x);
    return __builtin_bit_cast(float,
        __builtin_amdgcn_update_dpp(v, v, CTRL, 0xf, 0xf, false));
}
template<int CTRL>
__device__ __forceinline__ float dppmax(float m) {
    return fmaxf(m, dppmov<CTRL>(m));
}
__device__ __forceinline__ float rl(float v, int idx) {
    return __builtin_bit_cast(float,
        __builtin_amdgcn_readlane(__builtin_bit_cast(int, v), idx));
}

// One SGA recurrence step, all cross-lane via DPP.
// wave_shr:1 = 0x138 (lane0 keeps A -> d=0 clamp), wave_shl:1 = 0x130,
// row_shr:1/2/4/8 = 0x111/2/4/8, row_bcast:15 = 0x142, row_bcast:31 = 0x143.
__device__ __forceinline__ float sga_step_dpp(float A, float xi,
    float w0, float w1, float w2, float w3, float w4, bool actv, bool ge47)
{
    float up = dppmov<0x138>(A);             // A[d-1], lane0 clamps to A[0]
    float dn = dppmov<0x130>(A);             // A[d+1]
    dn = ge47 ? A : dn;                      // d=47 clamp (lanes 48-63 don't care)
    float m = actv ? A : -3.4e38f;
    m = dppmax<0x111>(m);
    m = dppmax<0x112>(m);
    m = dppmax<0x114>(m);
    m = dppmax<0x118>(m);                    // lane 15/31/47/63 = row max
    m = dppmax<0x142>(m);                    // accumulate across rows
    m = dppmax<0x143>(m);                    // lane 63 = full max
    float mall = rl(m, 63);
    return (w0*xi + w1*A) + ((w2*up + w3*dn) + w4*mall);
}

// ---------------------------------------------------------------------------
// Prep: L1-normalize guidance weights; repack conv weights into MFMA A-frag
// ---------------------------------------------------------------------------
__global__ __launch_bounds__(256) void prep_kernel(
    const float* __restrict__ g, const float* __restrict__ cw,
    float* __restrict__ wn, __hip_bfloat16* __restrict__ wrep)
{
    int idx = blockIdx.x * 256 + threadIdx.x;
    if (idx < 4 * HW_) {
        int dir = idx / HW_;
        int hw  = idx % HW_;
        const float* gb = g + dir * 5 * HW_ + hw;
        float v0 = gb[0*HW_], v1 = gb[1*HW_], v2 = gb[2*HW_], v3 = gb[3*HW_], v4 = gb[4*HW_];
        float s = fabsf(v0)+fabsf(v1)+fabsf(v2)+fabsf(v3)+fabsf(v4);
        float inv = 1.0f / fmaxf(s, 1e-12f);
        float* ob = wn + dir * 5 * HW_ + hw;
        ob[0*HW_] = v0*inv; ob[1*HW_] = v1*inv; ob[2*HW_] = v2*inv;
        ob[3*HW_] = v3*inv; ob[4*HW_] = v4*inv;
    } else {
        int j = idx - 4 * HW_;
        if (j < 2 * 27 * 64 * 8) {
            int e    = j & 7;
            int lane = (j >> 3) & 63;
            int tap  = (j >> 9) % 27;
            int ch   = j / (512 * 27);
            int co = ch * 16 + (lane & 15);
            int ci = (lane >> 4) * 8 + e;
            wrep[j] = __float2bfloat16(cw[(co * C_ + ci) * 27 + tap]);
        }
    }
}

// ---------------------------------------------------------------------------
// Horizontal scans (dir1 L->R, dir2 R->L). Block = 4 waves = 4 h rows.
// Weights live in per-lane registers (lane = p), broadcast via v_readlane.
// Writes max(d1,d2) into d12 (= d_out used as fp32 scratch).
// ---------------------------------------------------------------------------
__global__ __launch_bounds__(256) void sga_w_kernel(
    const float* __restrict__ x, const float* __restrict__ wn,
    float* __restrict__ d12)
{
    __shared__ float xbuf[48 * 257];     // [d][4h*64p], stride 257 (bank pad)
    int tid  = threadIdx.x;
    int lane = tid & 63;
    int hi   = tid >> 6;
    int c    = blockIdx.x >> 4;
    int h0   = (blockIdx.x & 15) * 4;
    int h    = h0 + hi;
    int d    = lane < 48 ? lane : 47;
    bool actv = lane < 48;
    bool ge47 = lane >= 47;

    float A = 0.0f;
    for (int dir = 0; dir < 2; ++dir) {
      for (int cc = 0; cc < 4; ++cc) {
        int ch = dir ? 3 - cc : cc;
        int p0 = ch * 64, len = (ch == 3) ? 16 : 64;
        // stage x tile [48 d][4 h][len p] (coalesced 256B runs)
        #pragma unroll
        for (int k = 0; k < 48; ++k) {
            int f = tid + 256 * k;
            int p = f & 63, hj = (f >> 6) & 3, dd = f >> 8;
            if (p < len)
                xbuf[dd * 257 + hj * 64 + p] =
                    x[((size_t)(c * 48 + dd) * 64 + h0 + hj) * 208 + p0 + p];
        }
        // per-wave weights into registers, lane = p
        int pl = p0 + (lane < len ? lane : len - 1);
        const float* wb = wn + (size_t)dir * 5 * HW_ + h * 208 + pl;
        float wv0 = wb[0], wv1 = wb[HW_], wv2 = wb[2*HW_], wv3 = wb[3*HW_], wv4 = wb[4*HW_];
        __syncthreads();
        float* xb = xbuf + d * 257 + hi * 64;
        if (dir == 0) {
            if (cc == 0) A = xb[0];
            #pragma unroll 4
            for (int p = 0; p < len; ++p) {
                float xi = xb[p];
                A = sga_step_dpp(A, xi, rl(wv0,p), rl(wv1,p), rl(wv2,p),
                                 rl(wv3,p), rl(wv4,p), actv, ge47);
                if (actv) xb[p] = A;
            }
        } else {
            if (cc == 0) A = xb[len - 1];
            #pragma unroll 4
            for (int p = len - 1; p >= 0; --p) {
                float xi = xb[p];
                A = sga_step_dpp(A, xi, rl(wv0,p), rl(wv1,p), rl(wv2,p),
                                 rl(wv3,p), rl(wv4,p), actv, ge47);
                if (actv) xb[p] = A;
            }
        }
        __syncthreads();
        // coalesced writeback (dir0: store, dir1: max-RMW)
        #pragma unroll
        for (int k = 0; k < 48; ++k) {
            int f = tid + 256 * k;
            int p = f & 63, hj = (f >> 6) & 3, dd = f >> 8;
            if (p < len) {
                size_t gi = ((size_t)(c * 48 + dd) * 64 + h0 + hj) * 208 + p0 + p;
                float v = xbuf[dd * 257 + hj * 64 + p];
                d12[gi] = dir ? fmaxf(d12[gi], v) : v;
            }
        }
        __syncthreads();
      }
    }
}

// ---------------------------------------------------------------------------
// Vertical scans (dir3 T->B, dir4 B->T). Block = 8 waves, 16 w columns,
// 2 columns per wave (ILP). 8-h chunks staged in LDS as float2 (64B lines).
// dir3 max-RMWs into d12; dir4 combines + BN1 + ReLU in place into d12.
// ---------------------------------------------------------------------------
__global__ __launch_bounds__(512) void sga_h_kernel(
    const float* __restrict__ x, const float* __restrict__ wn,
    float* __restrict__ d12,
    const float* __restrict__ g1, const float* __restrict__ b1,
    const float* __restrict__ m1, const float* __restrict__ v1)
{
    __shared__ float xbuf[48 * 130];     // [d][8h*16w], stride 130 (2-way free)
    int tid  = threadIdx.x;
    int lane = tid & 63;
    int wi   = tid >> 6;                 // wave -> columns 2wi, 2wi+1
    int c    = blockIdx.x / 13;
    int w0   = (blockIdx.x % 13) * 16;
    int d    = lane < 48 ? lane : 47;
    bool actv = lane < 48;
    bool ge47 = lane >= 47;
    int wa = 2 * wi, wb2 = 2 * wi + 1;

    float s1 = g1[c] * rsqrtf(v1[c] + EPS_);
    float o1 = b1[c] - m1[c] * s1;

    float A0 = 0.0f, A1 = 0.0f;
    for (int dir = 0; dir < 2; ++dir) {
      // weights into registers: lane l holds w_i[h=l] for this wave's columns
      const float* wbase = wn + (size_t)(2 + dir) * 5 * HW_ + lane * 208 + w0;
      float wva[5], wvb[5];
      #pragma unroll
      for (int i = 0; i < 5; ++i) {
          wva[i] = wbase[i * HW_ + wa];
          wvb[i] = wbase[i * HW_ + wb2];
      }
      for (int cc = 0; cc < 8; ++cc) {
        int ch = dir ? 7 - cc : cc;
        int h0 = ch * 8;
        // stage [48 d][8 h][16 w] via float2 (full 64B lines)
        #pragma unroll
        for (int k = 0; k < 6; ++k) {
            int f = tid + 512 * k;
            int wl = f & 7, hh = (f >> 3) & 7, dd = f >> 6;
            *(float2*)&xbuf[dd * 130 + hh * 16 + 2 * wl] =
                *(const float2*)&x[((size_t)(c*48+dd)*64 + h0+hh)*208 + w0 + 2*wl];
        }
        __syncthreads();
        float* xb = xbuf + d * 130;
        if (dir == 0) {
            if (cc == 0) { A0 = xb[wa]; A1 = xb[wb2]; }
            #pragma unroll
            for (int hh = 0; hh < 8; ++hh) {
                int hq = h0 + hh;
                float xa = xb[hh*16 + wa], xc = xb[hh*16 + wb2];
                A0 = sga_step_dpp(A0, xa, rl(wva[0],hq), rl(wva[1],hq), rl(wva[2],hq),
                                  rl(wva[3],hq), rl(wva[4],hq), actv, ge47);
                A1 = sga_step_dpp(A1, xc, rl(wvb[0],hq), rl(wvb[1],hq), rl(wvb[2],hq),
                                  rl(wvb[3],hq), rl(wvb[4],hq), actv, ge47);
                if (actv) { xb[hh*16 + wa] = A0; xb[hh*16 + wb2] = A1; }
            }
        } else {
            if (cc == 0) { A0 = xb[7*16 + wa]; A1 = xb[7*16 + wb2]; }
            #pragma unroll
            for (int hh = 7; hh >= 0; --hh) {
                int hq = h0 + hh;
                float xa = xb[hh*16 + wa], xc = xb[hh*16 + wb2];
                A0 = sga_step_dpp(A0, xa, rl(wva[0],hq), rl(wva[1],hq), rl(wva[2],hq),
                                  rl(wva[3],hq), rl(wva[4],hq), actv, ge47);
                A1 = sga_step_dpp(A1, xc, rl(wvb[0],hq), rl(wvb[1],hq), rl(wvb[2],hq),
                                  rl(wvb[3],hq), rl(wvb[4],hq), actv, ge47);
                if (actv) { xb[hh*16 + wa] = A0; xb[hh*16 + wb2] = A1; }
            }
        }
        __syncthreads();
        // writeback: dir0 max-RMW; dir1 combine + BN1 + ReLU (final, in place)
        #pragma unroll
        for (int k = 0; k < 6; ++k) {
            int f = tid + 512 * k;
            int wl = f & 7, hh = (f >> 3) & 7, dd = f >> 6;
            size_t gi = ((size_t)(c*48+dd)*64 + h0+hh)*208 + w0 + 2*wl;
            float2 v = *(float2*)&xbuf[dd * 130 + hh * 16 + 2 * wl];
            float2 o = *(float2*)&d12[gi];
            if (dir == 0) {
                o.x = fmaxf(o.x, v.x); o.y = fmaxf(o.y, v.y);
            } else {
                o.x = fmaxf(fmaxf(o.x, v.x) * s1 + o1, 0.0f);
                o.y = fmaxf(fmaxf(o.y, v.y) * s1 + o1, 0.0f);
            }
            *(float2*)&d12[gi] = o;
        }
        __syncthreads();
      }
    }
}

// ---------------------------------------------------------------------------
// Transpose: s fp32 [C][D][H][W] (in d_out) -> act bf16 [H][D][W][C] (in ws).
// ---------------------------------------------------------------------------
__global__ __launch_bounds__(256) void trans_kernel(
    const float* __restrict__ s, __hip_bfloat16* __restrict__ act)
{
    __shared__ float t[32 * 209];
    int tid = threadIdx.x;
    int d = blockIdx.x % 48;
    int h = blockIdx.x / 48;
    #pragma unroll
    for (int k = 0; k < 26; ++k) {
        int f = tid + 256 * k;           // f < 6656
        int wl = f % 208, ci = f / 208;
        t[ci * 209 + wl] = s[((size_t)(ci * 48 + d) * 64 + h) * 208 + wl];
    }
    __syncthreads();
    unsigned* actu = (unsigned*)act;
    #pragma unroll
    for (int k = 0; k < 13; ++k) {
        int f = tid + 256 * k;           // f < 3328
        int cp = f & 15, wl = f >> 4;
        union { unsigned u; __hip_bfloat16 hh[2]; } pk;
        pk.hh[0] = __float2bfloat16(t[(2 * cp) * 209 + wl]);
        pk.hh[1] = __float2bfloat16(t[(2 * cp + 1) * 209 + wl]);
        actu[((size_t)(h * 48 + d) * 208 + wl) * 16 + cp] = pk.u;
    }
}

// ---------------------------------------------------------------------------
// Conv 3x3x3 (C=32->32) as implicit GEMM on MFMA 16x16x32 bf16.
// ---------------------------------------------------------------------------
__global__ __launch_bounds__(256) void conv_kernel(
    const __hip_bfloat16* __restrict__ act,   // [H][D][W][C]
    const short8* __restrict__ wrep,          // [2][27][64] short8
    const float* __restrict__ x,
    const float* __restrict__ g2, const float* __restrict__ b2,
    const float* __restrict__ m2, const float* __restrict__ v2,
    float* __restrict__ out)
{
    int lane = threadIdx.x & 63;
    int wid  = blockIdx.x * 4 + (threadIdx.x >> 6);   // 0..79871
    int ch = wid & 1;
    int t1 = wid >> 1;
    int wt = t1 % 13;
    int t2 = t1 / 13;
    int d  = t2 % 48;
    int h  = t2 / 48;
    int w0 = wt * 16;
    int n   = lane & 15;
    int ci0 = (lane >> 4) * 8;

    float4v acc = {0.f, 0.f, 0.f, 0.f};
    const short8* wbase = wrep + (size_t)(ch * 27) * 64 + lane;

    #pragma unroll
    for (int kd = 0; kd < 3; ++kd) {
        int dd = d + kd - 1;
        if (dd < 0 || dd >= D_) continue;
        #pragma unroll
        for (int kh = 0; kh < 3; ++kh) {
            int hh = h + kh - 1;
            if (hh < 0 || hh >= H_) continue;
            const __hip_bfloat16* abase = act + ((size_t)(hh * D_ + dd) * W_) * C_;
            #pragma unroll
            for (int kw = 0; kw < 3; ++kw) {
                int ww = w0 + kw - 1 + n;
                int tap = (kd * 3 + kh) * 3 + kw;
                short8 bfrag = {0,0,0,0,0,0,0,0};
                if (ww >= 0 && ww < W_)
                    bfrag = *(const short8*)(abase + (size_t)ww * C_ + ci0);
                short8 afrag = wbase[tap * 64];
                acc = __builtin_amdgcn_mfma_f32_16x16x32_bf16(afrag, bfrag, acc, 0, 0, 0);
            }
        }
    }

    int cobase = ch * 16 + (lane >> 4) * 4;
    int wl = w0 + n;
    #pragma unroll
    for (int r = 0; r < 4; ++r) {
        int co = cobase + r;
        float s2 = g2[co] * rsqrtf(v2[co] + EPS_);
        float o2 = b2[co] - m2[co] * s2;
        size_t idx = ((size_t)(co * D_ + d) * H_ + h) * W_ + wl;
        out[idx] = fmaxf(acc[r] * s2 + o2 + x[idx], 0.0f);
    }
}

// ---------------------------------------------------------------------------
extern "C" void kernel_launch(void* const* d_in, const int* in_sizes, int n_in,
                              void* d_out, int out_size, void* d_ws, size_t ws_size,
                              hipStream_t stream)
{
    const float* x    = (const float*)d_in[0];
    const float* g    = (const float*)d_in[1];
    const float* cw   = (const float*)d_in[2];
    const float* bn1g = (const float*)d_in[3];
    const float* bn1b = (const float*)d_in[4];
    const float* bn1m = (const float*)d_in[5];
    const float* bn1v = (const float*)d_in[6];
    const float* bn2g = (const float*)d_in[7];
    const float* bn2b = (const float*)d_in[8];
    const float* bn2m = (const float*)d_in[9];
    const float* bn2v = (const float*)d_in[10];
    float* out = (float*)d_out;

    char* ws = (char*)d_ws;
    float* wn = (float*)ws;                                        // 1,064,960 B
    __hip_bfloat16* wrep = (__hip_bfloat16*)(ws + 1064960);        // 55,296 B
    __hip_bfloat16* act  = (__hip_bfloat16*)(ws + 1064960 + 55296);// 40.9 MB

    // 1) normalize guidance + repack conv weights
    prep_kernel<<<316, 256, 0, stream>>>(g, cw, wn, wrep);
    // 2) horizontal scans -> max(d1,d2) into d_out (fp32 scratch)
    sga_w_kernel<<<512, 256, 0, stream>>>(x, wn, out);
    // 3) vertical scans + combine + BN1 + ReLU -> fp32, in place in d_out
    sga_h_kernel<<<416, 512, 0, stream>>>(x, wn, out, bn1g, bn1b, bn1m, bn1v);
    // 4) transpose to bf16 act [H][D][W][C]
    trans_kernel<<<3072, 256, 0, stream>>>(out, act);
    // 5) conv 3x3x3 (MFMA) + BN2 + residual + ReLU -> d_out
    conv_kernel<<<19968, 256, 0, stream>>>(act, (const short8*)wrep, x,
                                           bn2g, bn2b, bn2m, bn2v, out);
}

// Round 4
// 535.381 us; speedup vs baseline: 2.6870x; 1.4165x over previous
//
#include <hip/hip_runtime.h>
#include <hip/hip_bf16.h>
#include <cstddef>

#define C_ 32
#define D_ 48
#define H_ 64
#define W_ 208
#define HW_ 13312            // H_*W_
#define HS_ 9984             // W_*48, xt h-stride
#define EPS_ 1e-5f

typedef __attribute__((ext_vector_type(8))) short short8;
typedef __attribute__((ext_vector_type(4))) float float4v;

// ---------------------------------------------------------------------------
// DPP helpers (VALU-latency cross-lane; invalid lanes keep old = src)
// ---------------------------------------------------------------------------
template<int CTRL>
__device__ __forceinline__ float dppmov(float x) {
    int v = __builtin_bit_cast(int, x);
    return __builtin_bit_cast(float,
        __builtin_amdgcn_update_dpp(v, v, CTRL, 0xf, 0xf, false));
}
template<int CTRL>
__device__ __forceinline__ float dppmax(float m) {
    return fmaxf(m, dppmov<CTRL>(m));
}
__device__ __forceinline__ float rl(float v, int idx) {
    return __builtin_bit_cast(float,
        __builtin_amdgcn_readlane(__builtin_bit_cast(int, v), idx));
}

// One SGA recurrence step, all cross-lane via DPP (lane = d).
__device__ __forceinline__ float sga_step_dpp(float A, float xi,
    float w0, float w1, float w2, float w3, float w4, bool actv, bool ge47)
{
    float up = dppmov<0x138>(A);             // wave_shr:1, lane0 keeps A (d=0 clamp)
    float dn = dppmov<0x130>(A);             // wave_shl:1
    dn = ge47 ? A : dn;                      // d=47 clamp
    float m = actv ? A : -3.4e38f;
    m = dppmax<0x111>(m);
    m = dppmax<0x112>(m);
    m = dppmax<0x114>(m);
    m = dppmax<0x118>(m);
    m = dppmax<0x142>(m);
    m = dppmax<0x143>(m);
    float mall = rl(m, 63);
    return (w0*xi + w1*A) + ((w2*up + w3*dn) + w4*mall);
}

// ---------------------------------------------------------------------------
// Prep: L1-normalize guidance; transpose H-scan weights to [dd][i][w][h];
// repack conv weights into MFMA A-frag layout.
// ---------------------------------------------------------------------------
__global__ __launch_bounds__(256) void prep_kernel(
    const float* __restrict__ g, const float* __restrict__ cw,
    float* __restrict__ wn, float* __restrict__ wnT,
    __hip_bfloat16* __restrict__ wrep)
{
    int idx = blockIdx.x * 256 + threadIdx.x;
    if (idx < 4 * HW_) {
        int dir = idx / HW_;
        int hw  = idx % HW_;
        const float* gb = g + dir * 5 * HW_ + hw;
        float v0 = gb[0*HW_], v1 = gb[1*HW_], v2 = gb[2*HW_], v3 = gb[3*HW_], v4 = gb[4*HW_];
        float s = fabsf(v0)+fabsf(v1)+fabsf(v2)+fabsf(v3)+fabsf(v4);
        float inv = 1.0f / fmaxf(s, 1e-12f);
        v0 *= inv; v1 *= inv; v2 *= inv; v3 *= inv; v4 *= inv;
        float* ob = wn + dir * 5 * HW_ + hw;
        ob[0*HW_] = v0; ob[1*HW_] = v1; ob[2*HW_] = v2; ob[3*HW_] = v3; ob[4*HW_] = v4;
        if (dir >= 2) {   // H-scan dirs: also write [dd][i][w][h]
            int hq = hw / W_, wq = hw % W_;
            float* oT = wnT + ((size_t)((dir-2)*5)*W_ + wq)*H_ + hq;
            oT[0]       = v0; oT[1*HW_] = v1; oT[2*HW_] = v2;
            oT[3*HW_]   = v3; oT[4*HW_] = v4;   // i-stride = W_*H_ = HW_
        }
    } else {
        int j = idx - 4 * HW_;
        if (j < 2 * 27 * 64 * 8) {
            int e    = j & 7;
            int lane = (j >> 3) & 63;
            int tap  = (j >> 9) % 27;
            int ch   = j / (512 * 27);
            int co = ch * 16 + (lane & 15);
            int ci = (lane >> 4) * 8 + e;
            wrep[j] = __float2bfloat16(cw[(co * C_ + ci) * 27 + tap]);
        }
    }
}

// ---------------------------------------------------------------------------
// t0: transpose x [c][d][h][w] -> xt [c][h][w][d] (fp32, lives in d_out)
// ---------------------------------------------------------------------------
__global__ __launch_bounds__(256) void t0_kernel(
    const float* __restrict__ x, float* __restrict__ xt)
{
    __shared__ float t[48 * 257];
    int tid = threadIdx.x;
    int c  = blockIdx.x / 52;
    int q0 = (blockIdx.x % 52) * 256;
    #pragma unroll
    for (int dd = 0; dd < 48; ++dd)
        t[dd * 257 + tid] = x[((size_t)c * 48 + dd) * HW_ + q0 + tid];
    __syncthreads();
    #pragma unroll
    for (int k = 0; k < 48; ++k) {
        int f = tid + 256 * k;              // < 12288
        int dd = f % 48, hwl = f / 48;
        xt[((size_t)c * HW_ + q0 + hwl) * 48 + dd] = t[dd * 257 + hwl];
    }
}

// ---------------------------------------------------------------------------
// Register-chunked scan helpers over the d-innermost layout.
// elem stride between steps = 48; results as bf16 into dp.
// ---------------------------------------------------------------------------
template<int LN>
__device__ __forceinline__ float chunk_fwd(float A,
    const float* __restrict__ xp, __hip_bfloat16* __restrict__ dp,
    const float* __restrict__ wb, int P0, int lane, bool actv, bool ge47)
{
    float xr[LN];
    #pragma unroll
    for (int j = 0; j < LN; ++j) xr[j] = xp[(size_t)(P0 + j) * 48];
    int lm = lane & (LN - 1);
    float wv0 = wb[0*HW_ + P0 + lm], wv1 = wb[1*HW_ + P0 + lm],
          wv2 = wb[2*HW_ + P0 + lm], wv3 = wb[3*HW_ + P0 + lm],
          wv4 = wb[4*HW_ + P0 + lm];
    #pragma unroll
    for (int j = 0; j < LN; ++j) {
        A = sga_step_dpp(A, xr[j], rl(wv0,j), rl(wv1,j), rl(wv2,j),
                         rl(wv3,j), rl(wv4,j), actv, ge47);
        if (actv) dp[(size_t)(P0 + j) * 48] = __float2bfloat16(A);
    }
    return A;
}

template<int LN>
__device__ __forceinline__ float chunk_rev(float A,
    const float* __restrict__ xp, __hip_bfloat16* __restrict__ dp,
    const float* __restrict__ wb, int P0, int lane, bool actv, bool ge47)
{
    float xr[LN]; __hip_bfloat16 dr[LN];
    #pragma unroll
    for (int j = 0; j < LN; ++j) {
        xr[j] = xp[(size_t)(P0 + j) * 48];
        dr[j] = dp[(size_t)(P0 + j) * 48];
    }
    int lm = lane & (LN - 1);
    float wv0 = wb[0*HW_ + P0 + lm], wv1 = wb[1*HW_ + P0 + lm],
          wv2 = wb[2*HW_ + P0 + lm], wv3 = wb[3*HW_ + P0 + lm],
          wv4 = wb[4*HW_ + P0 + lm];
    #pragma unroll
    for (int j = LN - 1; j >= 0; --j) {
        A = sga_step_dpp(A, xr[j], rl(wv0,j), rl(wv1,j), rl(wv2,j),
                         rl(wv3,j), rl(wv4,j), actv, ge47);
        if (actv)
            dp[(size_t)(P0 + j) * 48] =
                __float2bfloat16(fmaxf(__bfloat162float(dr[j]), A));
    }
    return A;
}

// ---------------------------------------------------------------------------
// Horizontal scans: 2048 independent waves (c,h). No LDS, no barriers.
// dir1 stores d1 bf16 -> d12t[c][h][w][d]; dir2 loads+max+stores in place.
// ---------------------------------------------------------------------------
__global__ __launch_bounds__(256) void sga_w_kernel(
    const float* __restrict__ xt, const float* __restrict__ wn,
    __hip_bfloat16* __restrict__ d12)
{
    int lane = threadIdx.x & 63;
    int wid  = blockIdx.x * 4 + (threadIdx.x >> 6);   // 0..2047
    int c = wid >> 6, h = wid & 63;
    int d = lane < 48 ? lane : 47;
    bool actv = lane < 48, ge47 = lane >= 47;
    const float* xp = xt + ((size_t)c * HW_ + h * W_) * 48 + d;
    __hip_bfloat16* dp = d12 + ((size_t)c * HW_ + h * W_) * 48 + d;
    const float* w1 = wn + (size_t)0 * 5 * HW_ + h * W_;
    const float* w2 = wn + (size_t)1 * 5 * HW_ + h * W_;

    // dir 1: left -> right
    float A = xp[0];
    for (int cc = 0; cc < 6; ++cc)
        A = chunk_fwd<32>(A, xp, dp, w1, cc * 32, lane, actv, ge47);
    A = chunk_fwd<16>(A, xp, dp, w1, 192, lane, actv, ge47);

    // dir 2: right -> left
    A = xp[(size_t)207 * 48];
    A = chunk_rev<16>(A, xp, dp, w2, 192, lane, actv, ge47);
    for (int cc = 0; cc < 6; ++cc)
        A = chunk_rev<32>(A, xp, dp, w2, 160 - cc * 32, lane, actv, ge47);
}

// ---------------------------------------------------------------------------
// Vertical scans: 6656 independent waves (c,w). dir3 -> 64 registers;
// dir4 combines d3/d4/d12 + BN1 + ReLU, overwrites d12t in place (bf16).
// ---------------------------------------------------------------------------
__global__ __launch_bounds__(256) void sga_h_kernel(
    const float* __restrict__ xt, const float* __restrict__ wnT,
    __hip_bfloat16* __restrict__ d12,
    const float* __restrict__ g1, const float* __restrict__ b1,
    const float* __restrict__ m1, const float* __restrict__ v1)
{
    int lane = threadIdx.x & 63;
    int wid  = blockIdx.x * 4 + (threadIdx.x >> 6);   // 0..6655
    int c = wid / W_, w = wid % W_;
    int d = lane < 48 ? lane : 47;
    bool actv = lane < 48, ge47 = lane >= 47;
    const float* xp = xt + ((size_t)c * HW_ + w) * 48 + d;   // step h: + h*HS_
    __hip_bfloat16* dp = d12 + ((size_t)c * HW_ + w) * 48 + d;
    const float* w3 = wnT + ((size_t)0 * W_ + w) * H_;       // + i*HW_ + h
    const float* w4 = wnT + ((size_t)5 * W_ + w) * H_;

    float s1 = g1[c] * rsqrtf(v1[c] + EPS_);
    float o1 = b1[c] - m1[c] * s1;

    float d3v[64];
    // dir 3: top -> bottom (results stay in registers)
    float A = xp[0];
    #pragma unroll
    for (int cc = 0; cc < 4; ++cc) {
        int h0 = cc * 16;
        float xr[16];
        #pragma unroll
        for (int j = 0; j < 16; ++j) xr[j] = xp[(size_t)(h0 + j) * HS_];
        int lm = lane & 15;
        float wv0 = w3[0*HW_ + h0 + lm], wv1 = w3[1*HW_ + h0 + lm],
              wv2 = w3[2*HW_ + h0 + lm], wv3 = w3[3*HW_ + h0 + lm],
              wv4 = w3[4*HW_ + h0 + lm];
        #pragma unroll
        for (int j = 0; j < 16; ++j) {
            A = sga_step_dpp(A, xr[j], rl(wv0,j), rl(wv1,j), rl(wv2,j),
                             rl(wv3,j), rl(wv4,j), actv, ge47);
            d3v[h0 + j] = A;
        }
    }
    // dir 4: bottom -> top; combine + BN1 + ReLU, in place into d12t
    A = xp[(size_t)63 * HS_];
    #pragma unroll
    for (int cc = 0; cc < 4; ++cc) {
        int h0 = 48 - cc * 16;
        float xr[16]; __hip_bfloat16 dr[16];
        #pragma unroll
        for (int j = 0; j < 16; ++j) {
            xr[j] = xp[(size_t)(h0 + j) * HS_];
            dr[j] = dp[(size_t)(h0 + j) * HS_];
        }
        int lm = lane & 15;
        float wv0 = w4[0*HW_ + h0 + lm], wv1 = w4[1*HW_ + h0 + lm],
              wv2 = w4[2*HW_ + h0 + lm], wv3 = w4[3*HW_ + h0 + lm],
              wv4 = w4[4*HW_ + h0 + lm];
        #pragma unroll
        for (int j = 15; j >= 0; --j) {
            A = sga_step_dpp(A, xr[j], rl(wv0,j), rl(wv1,j), rl(wv2,j),
                             rl(wv3,j), rl(wv4,j), actv, ge47);
            if (actv) {
                float comb = fmaxf(fmaxf(d3v[h0 + j], A), __bfloat162float(dr[j]));
                dp[(size_t)(h0 + j) * HS_] =
                    __float2bfloat16(fmaxf(comb * s1 + o1, 0.0f));
            }
        }
    }
}

// ---------------------------------------------------------------------------
// trans: st bf16 [c][h][w][d] -> act bf16 [h][d][w][c] (LDS tiled)
// ---------------------------------------------------------------------------
__global__ __launch_bounds__(256) void trans_kernel(
    const __hip_bfloat16* __restrict__ st, __hip_bfloat16* __restrict__ act)
{
    __shared__ float t[8 * 1571];   // addr = wl*1571 + c*49 + d
    int tid = threadIdx.x;
    int h  = blockIdx.x / 26;
    int w0 = (blockIdx.x % 26) * 8;
    const unsigned* stu = (const unsigned*)st;
    #pragma unroll
    for (int k = 0; k < 24; ++k) {
        int f = tid + 256 * k;              // < 6144
        int d2 = f % 24, wl = (f / 24) % 8, c = f / 192;
        unsigned u = stu[(((size_t)c * HW_ + h * W_ + w0 + wl) * 48 + 2 * d2) >> 1];
        const __hip_bfloat16* bp = (const __hip_bfloat16*)&u;
        t[wl * 1571 + c * 49 + 2 * d2]     = __bfloat162float(bp[0]);
        t[wl * 1571 + c * 49 + 2 * d2 + 1] = __bfloat162float(bp[1]);
    }
    __syncthreads();
    unsigned* actu = (unsigned*)act;
    #pragma unroll
    for (int k = 0; k < 24; ++k) {
        int f = tid + 256 * k;              // < 6144
        int cp = f % 16, wl = (f / 16) % 8, d = f / 128;
        union { unsigned u; __hip_bfloat16 hh[2]; } pk;
        pk.hh[0] = __float2bfloat16(t[wl * 1571 + (2 * cp) * 49 + d]);
        pk.hh[1] = __float2bfloat16(t[wl * 1571 + (2 * cp + 1) * 49 + d]);
        actu[(((size_t)h * 48 + d) * W_ + w0 + wl) * 16 + cp] = pk.u;
    }
}

// ---------------------------------------------------------------------------
// Conv 3x3x3 (C=32->32) as implicit GEMM on MFMA 16x16x32 bf16.
// ---------------------------------------------------------------------------
__global__ __launch_bounds__(256) void conv_kernel(
    const __hip_bfloat16* __restrict__ act,   // [H][D][W][C]
    const short8* __restrict__ wrep,          // [2][27][64] short8
    const float* __restrict__ x,
    const float* __restrict__ g2, const float* __restrict__ b2,
    const float* __restrict__ m2, const float* __restrict__ v2,
    float* __restrict__ out)
{
    int lane = threadIdx.x & 63;
    int wid  = blockIdx.x * 4 + (threadIdx.x >> 6);   // 0..79871
    int ch = wid & 1;
    int t1 = wid >> 1;
    int wt = t1 % 13;
    int t2 = t1 / 13;
    int d  = t2 % 48;
    int h  = t2 / 48;
    int w0 = wt * 16;
    int n   = lane & 15;
    int ci0 = (lane >> 4) * 8;

    float4v acc = {0.f, 0.f, 0.f, 0.f};
    const short8* wbase = wrep + (size_t)(ch * 27) * 64 + lane;

    #pragma unroll
    for (int kd = 0; kd < 3; ++kd) {
        int dd = d + kd - 1;
        if (dd < 0 || dd >= D_) continue;
        #pragma unroll
        for (int kh = 0; kh < 3; ++kh) {
            int hh = h + kh - 1;
            if (hh < 0 || hh >= H_) continue;
            const __hip_bfloat16* abase = act + ((size_t)(hh * D_ + dd) * W_) * C_;
            #pragma unroll
            for (int kw = 0; kw < 3; ++kw) {
                int ww = w0 + kw - 1 + n;
                int tap = (kd * 3 + kh) * 3 + kw;
                short8 bfrag = {0,0,0,0,0,0,0,0};
                if (ww >= 0 && ww < W_)
                    bfrag = *(const short8*)(abase + (size_t)ww * C_ + ci0);
                short8 afrag = wbase[tap * 64];
                acc = __builtin_amdgcn_mfma_f32_16x16x32_bf16(afrag, bfrag, acc, 0, 0, 0);
            }
        }
    }

    int cobase = ch * 16 + (lane >> 4) * 4;
    int wl = w0 + n;
    #pragma unroll
    for (int r = 0; r < 4; ++r) {
        int co = cobase + r;
        float s2 = g2[co] * rsqrtf(v2[co] + EPS_);
        float o2 = b2[co] - m2[co] * s2;
        size_t idx = ((size_t)(co * D_ + d) * H_ + h) * W_ + wl;
        out[idx] = fmaxf(acc[r] * s2 + o2 + x[idx], 0.0f);
    }
}

// ---------------------------------------------------------------------------
extern "C" void kernel_launch(void* const* d_in, const int* in_sizes, int n_in,
                              void* d_out, int out_size, void* d_ws, size_t ws_size,
                              hipStream_t stream)
{
    const float* x    = (const float*)d_in[0];
    const float* g    = (const float*)d_in[1];
    const float* cw   = (const float*)d_in[2];
    const float* bn1g = (const float*)d_in[3];
    const float* bn1b = (const float*)d_in[4];
    const float* bn1m = (const float*)d_in[5];
    const float* bn1v = (const float*)d_in[6];
    const float* bn2g = (const float*)d_in[7];
    const float* bn2b = (const float*)d_in[8];
    const float* bn2m = (const float*)d_in[9];
    const float* bn2v = (const float*)d_in[10];
    float* out = (float*)d_out;

    char* ws = (char*)d_ws;
    float* wn  = (float*)ws;                                   // 1,064,960 B
    float* wnT = (float*)(ws + 1064960);                       //   532,480 B
    __hip_bfloat16* wrep = (__hip_bfloat16*)(ws + 1597440);    //    55,296 B
    __hip_bfloat16* d12t = (__hip_bfloat16*)(ws + 1652736);    // 40,894,464 B
    __hip_bfloat16* act  = (__hip_bfloat16*)(ws + 42547200);   // 40,894,464 B
    float* xt = out;   // d_out doubles as fp32 xt scratch; dead before conv

    // 1) normalize guidance (+ wnT transpose) + repack conv weights
    prep_kernel<<<316, 256, 0, stream>>>(g, cw, wn, wnT, wrep);
    // 2) transpose x -> xt [c][h][w][d]
    t0_kernel<<<1664, 256, 0, stream>>>(x, xt);
    // 3) horizontal scans -> max(d1,d2) bf16 in d12t (barrier-free)
    sga_w_kernel<<<512, 256, 0, stream>>>(xt, wn, d12t);
    // 4) vertical scans + combine + BN1 + ReLU -> bf16, in place in d12t
    sga_h_kernel<<<1664, 256, 0, stream>>>(xt, wnT, d12t, bn1g, bn1b, bn1m, bn1v);
    // 5) relayout to act [h][d][w][c]
    trans_kernel<<<1664, 256, 0, stream>>>(d12t, act);
    // 6) conv 3x3x3 (MFMA) + BN2 + residual + ReLU -> d_out
    conv_kernel<<<19968, 256, 0, stream>>>(act, (const short8*)wrep, x,
                                           bn2g, bn2b, bn2m, bn2v, out);
}

// Round 5
// 449.203 us; speedup vs baseline: 3.2025x; 1.1918x over previous
//
#include <hip/hip_runtime.h>
#include <hip/hip_bf16.h>
#include <cstddef>

#define C_ 32
#define D_ 48
#define H_ 64
#define W_ 208
#define HW_ 13312            // H_*W_
#define HS_ 9984             // W_*48, xt h-stride
#define EPS_ 1e-5f

typedef __attribute__((ext_vector_type(8))) short short8;
typedef __attribute__((ext_vector_type(4))) float float4v;
typedef __attribute__((ext_vector_type(16))) float float16v;

// ---------------------------------------------------------------------------
// DPP helpers (VALU-latency cross-lane; invalid lanes keep old = src)
// ---------------------------------------------------------------------------
template<int CTRL>
__device__ __forceinline__ float dppmov(float x) {
    int v = __builtin_bit_cast(int, x);
    return __builtin_bit_cast(float,
        __builtin_amdgcn_update_dpp(v, v, CTRL, 0xf, 0xf, false));
}
template<int CTRL>
__device__ __forceinline__ float dppmax(float m) {
    return fmaxf(m, dppmov<CTRL>(m));
}
__device__ __forceinline__ float rl(float v, int idx) {
    return __builtin_bit_cast(float,
        __builtin_amdgcn_readlane(__builtin_bit_cast(int, v), idx));
}

// One SGA recurrence step, all cross-lane via DPP (lane = d).
__device__ __forceinline__ float sga_step_dpp(float A, float xi,
    float w0, float w1, float w2, float w3, float w4, bool actv, bool ge47)
{
    float up = dppmov<0x138>(A);             // wave_shr:1, lane0 keeps A (d=0 clamp)
    float dn = dppmov<0x130>(A);             // wave_shl:1
    dn = ge47 ? A : dn;                      // d=47 clamp
    float m = actv ? A : -3.4e38f;
    m = dppmax<0x111>(m);
    m = dppmax<0x112>(m);
    m = dppmax<0x114>(m);
    m = dppmax<0x118>(m);
    m = dppmax<0x142>(m);
    m = dppmax<0x143>(m);
    float mall = rl(m, 63);
    return (w0*xi + w1*A) + ((w2*up + w3*dn) + w4*mall);
}

// ---------------------------------------------------------------------------
// Prep: L1-normalize guidance; transpose H-scan weights to [dd][i][w][h];
// repack conv weights into 32x32x16 MFMA A-frag layout:
// wrep[((tap*2+cih)*64+lane)*8+e] = w[co=lane&31][ci=cih*16+(lane>>5)*8+e][tap]
// ---------------------------------------------------------------------------
__global__ __launch_bounds__(256) void prep_kernel(
    const float* __restrict__ g, const float* __restrict__ cw,
    float* __restrict__ wn, float* __restrict__ wnT,
    __hip_bfloat16* __restrict__ wrep)
{
    int idx = blockIdx.x * 256 + threadIdx.x;
    if (idx < 4 * HW_) {
        int dir = idx / HW_;
        int hw  = idx % HW_;
        const float* gb = g + dir * 5 * HW_ + hw;
        float v0 = gb[0*HW_], v1 = gb[1*HW_], v2 = gb[2*HW_], v3 = gb[3*HW_], v4 = gb[4*HW_];
        float s = fabsf(v0)+fabsf(v1)+fabsf(v2)+fabsf(v3)+fabsf(v4);
        float inv = 1.0f / fmaxf(s, 1e-12f);
        v0 *= inv; v1 *= inv; v2 *= inv; v3 *= inv; v4 *= inv;
        float* ob = wn + dir * 5 * HW_ + hw;
        ob[0*HW_] = v0; ob[1*HW_] = v1; ob[2*HW_] = v2; ob[3*HW_] = v3; ob[4*HW_] = v4;
        if (dir >= 2) {   // H-scan dirs: also write [dd][i][w][h]
            int hq = hw / W_, wq = hw % W_;
            float* oT = wnT + ((size_t)((dir-2)*5)*W_ + wq)*H_ + hq;
            oT[0]       = v0; oT[1*HW_] = v1; oT[2*HW_] = v2;
            oT[3*HW_]   = v3; oT[4*HW_] = v4;   // i-stride = W_*H_ = HW_
        }
    } else {
        int j = idx - 4 * HW_;
        if (j < 27 * 2 * 64 * 8) {
            int e    = j & 7;
            int lane = (j >> 3) & 63;
            int q    = j >> 9;            // 0..53
            int cih  = q & 1;
            int tap  = q >> 1;
            int co = lane & 31;
            int ci = cih * 16 + (lane >> 5) * 8 + e;
            wrep[j] = __float2bfloat16(cw[(co * C_ + ci) * 27 + tap]);
        }
    }
}

// ---------------------------------------------------------------------------
// t0: transpose x [c][d][h][w] -> xt [c][h][w][d] (fp32, lives in d_out)
// ---------------------------------------------------------------------------
__global__ __launch_bounds__(256) void t0_kernel(
    const float* __restrict__ x, float* __restrict__ xt)
{
    __shared__ float t[48 * 257];
    int tid = threadIdx.x;
    int c  = blockIdx.x / 52;
    int q0 = (blockIdx.x % 52) * 256;
    #pragma unroll
    for (int dd = 0; dd < 48; ++dd)
        t[dd * 257 + tid] = x[((size_t)c * 48 + dd) * HW_ + q0 + tid];
    __syncthreads();
    #pragma unroll
    for (int k = 0; k < 48; ++k) {
        int f = tid + 256 * k;              // < 12288
        int dd = f % 48, hwl = f / 48;
        xt[((size_t)c * HW_ + q0 + hwl) * 48 + dd] = t[dd * 257 + hwl];
    }
}

// ---------------------------------------------------------------------------
// Register-chunked scan helpers over the d-innermost layout.
// ---------------------------------------------------------------------------
template<int LN>
__device__ __forceinline__ float chunk_fwd(float A,
    const float* __restrict__ xp, __hip_bfloat16* __restrict__ dp,
    const float* __restrict__ wb, int P0, int lane, bool actv, bool ge47)
{
    float xr[LN];
    #pragma unroll
    for (int j = 0; j < LN; ++j) xr[j] = xp[(size_t)(P0 + j) * 48];
    int lm = lane & (LN - 1);
    float wv0 = wb[0*HW_ + P0 + lm], wv1 = wb[1*HW_ + P0 + lm],
          wv2 = wb[2*HW_ + P0 + lm], wv3 = wb[3*HW_ + P0 + lm],
          wv4 = wb[4*HW_ + P0 + lm];
    #pragma unroll
    for (int j = 0; j < LN; ++j) {
        A = sga_step_dpp(A, xr[j], rl(wv0,j), rl(wv1,j), rl(wv2,j),
                         rl(wv3,j), rl(wv4,j), actv, ge47);
        if (actv) dp[(size_t)(P0 + j) * 48] = __float2bfloat16(A);
    }
    return A;
}

template<int LN>
__device__ __forceinline__ float chunk_rev(float A,
    const float* __restrict__ xp, __hip_bfloat16* __restrict__ dp,
    const float* __restrict__ wb, int P0, int lane, bool actv, bool ge47)
{
    float xr[LN]; __hip_bfloat16 dr[LN];
    #pragma unroll
    for (int j = 0; j < LN; ++j) {
        xr[j] = xp[(size_t)(P0 + j) * 48];
        dr[j] = dp[(size_t)(P0 + j) * 48];
    }
    int lm = lane & (LN - 1);
    float wv0 = wb[0*HW_ + P0 + lm], wv1 = wb[1*HW_ + P0 + lm],
          wv2 = wb[2*HW_ + P0 + lm], wv3 = wb[3*HW_ + P0 + lm],
          wv4 = wb[4*HW_ + P0 + lm];
    #pragma unroll
    for (int j = LN - 1; j >= 0; --j) {
        A = sga_step_dpp(A, xr[j], rl(wv0,j), rl(wv1,j), rl(wv2,j),
                         rl(wv3,j), rl(wv4,j), actv, ge47);
        if (actv)
            dp[(size_t)(P0 + j) * 48] =
                __float2bfloat16(fmaxf(__bfloat162float(dr[j]), A));
    }
    return A;
}

// ---------------------------------------------------------------------------
// Horizontal scans: 2048 independent waves (c,h). No LDS, no barriers.
// ---------------------------------------------------------------------------
__global__ __launch_bounds__(256) void sga_w_kernel(
    const float* __restrict__ xt, const float* __restrict__ wn,
    __hip_bfloat16* __restrict__ d12)
{
    int lane = threadIdx.x & 63;
    int wid  = blockIdx.x * 4 + (threadIdx.x >> 6);   // 0..2047
    int c = wid >> 6, h = wid & 63;
    int d = lane < 48 ? lane : 47;
    bool actv = lane < 48, ge47 = lane >= 47;
    const float* xp = xt + ((size_t)c * HW_ + h * W_) * 48 + d;
    __hip_bfloat16* dp = d12 + ((size_t)c * HW_ + h * W_) * 48 + d;
    const float* w1 = wn + (size_t)0 * 5 * HW_ + h * W_;
    const float* w2 = wn + (size_t)1 * 5 * HW_ + h * W_;

    float A = xp[0];
    for (int cc = 0; cc < 6; ++cc)
        A = chunk_fwd<32>(A, xp, dp, w1, cc * 32, lane, actv, ge47);
    A = chunk_fwd<16>(A, xp, dp, w1, 192, lane, actv, ge47);

    A = xp[(size_t)207 * 48];
    A = chunk_rev<16>(A, xp, dp, w2, 192, lane, actv, ge47);
    for (int cc = 0; cc < 6; ++cc)
        A = chunk_rev<32>(A, xp, dp, w2, 160 - cc * 32, lane, actv, ge47);
}

// ---------------------------------------------------------------------------
// Vertical scans: 6656 independent waves (c,w).
// ---------------------------------------------------------------------------
__global__ __launch_bounds__(256) void sga_h_kernel(
    const float* __restrict__ xt, const float* __restrict__ wnT,
    __hip_bfloat16* __restrict__ d12,
    const float* __restrict__ g1, const float* __restrict__ b1,
    const float* __restrict__ m1, const float* __restrict__ v1)
{
    int lane = threadIdx.x & 63;
    int wid  = blockIdx.x * 4 + (threadIdx.x >> 6);   // 0..6655
    int c = wid / W_, w = wid % W_;
    int d = lane < 48 ? lane : 47;
    bool actv = lane < 48, ge47 = lane >= 47;
    const float* xp = xt + ((size_t)c * HW_ + w) * 48 + d;   // step h: + h*HS_
    __hip_bfloat16* dp = d12 + ((size_t)c * HW_ + w) * 48 + d;
    const float* w3 = wnT + ((size_t)0 * W_ + w) * H_;       // + i*HW_ + h
    const float* w4 = wnT + ((size_t)5 * W_ + w) * H_;

    float s1 = g1[c] * rsqrtf(v1[c] + EPS_);
    float o1 = b1[c] - m1[c] * s1;

    float d3v[64];
    float A = xp[0];
    #pragma unroll
    for (int cc = 0; cc < 4; ++cc) {
        int h0 = cc * 16;
        float xr[16];
        #pragma unroll
        for (int j = 0; j < 16; ++j) xr[j] = xp[(size_t)(h0 + j) * HS_];
        int lm = lane & 15;
        float wv0 = w3[0*HW_ + h0 + lm], wv1 = w3[1*HW_ + h0 + lm],
              wv2 = w3[2*HW_ + h0 + lm], wv3 = w3[3*HW_ + h0 + lm],
              wv4 = w3[4*HW_ + h0 + lm];
        #pragma unroll
        for (int j = 0; j < 16; ++j) {
            A = sga_step_dpp(A, xr[j], rl(wv0,j), rl(wv1,j), rl(wv2,j),
                             rl(wv3,j), rl(wv4,j), actv, ge47);
            d3v[h0 + j] = A;
        }
    }
    A = xp[(size_t)63 * HS_];
    #pragma unroll
    for (int cc = 0; cc < 4; ++cc) {
        int h0 = 48 - cc * 16;
        float xr[16]; __hip_bfloat16 dr[16];
        #pragma unroll
        for (int j = 0; j < 16; ++j) {
            xr[j] = xp[(size_t)(h0 + j) * HS_];
            dr[j] = dp[(size_t)(h0 + j) * HS_];
        }
        int lm = lane & 15;
        float wv0 = w4[0*HW_ + h0 + lm], wv1 = w4[1*HW_ + h0 + lm],
              wv2 = w4[2*HW_ + h0 + lm], wv3 = w4[3*HW_ + h0 + lm],
              wv4 = w4[4*HW_ + h0 + lm];
        #pragma unroll
        for (int j = 15; j >= 0; --j) {
            A = sga_step_dpp(A, xr[j], rl(wv0,j), rl(wv1,j), rl(wv2,j),
                             rl(wv3,j), rl(wv4,j), actv, ge47);
            if (actv) {
                float comb = fmaxf(fmaxf(d3v[h0 + j], A), __bfloat162float(dr[j]));
                dp[(size_t)(h0 + j) * HS_] =
                    __float2bfloat16(fmaxf(comb * s1 + o1, 0.0f));
            }
        }
    }
}

// ---------------------------------------------------------------------------
// trans: st bf16 [c][h][w][d] -> act bf16 [h][d][w][c] (LDS tiled)
// ---------------------------------------------------------------------------
__global__ __launch_bounds__(256) void trans_kernel(
    const __hip_bfloat16* __restrict__ st, __hip_bfloat16* __restrict__ act)
{
    __shared__ float t[8 * 1571];   // addr = wl*1571 + c*49 + d
    int tid = threadIdx.x;
    int h  = blockIdx.x / 26;
    int w0 = (blockIdx.x % 26) * 8;
    const unsigned* stu = (const unsigned*)st;
    #pragma unroll
    for (int k = 0; k < 24; ++k) {
        int f = tid + 256 * k;              // < 6144
        int d2 = f % 24, wl = (f / 24) % 8, c = f / 192;
        unsigned u = stu[(((size_t)c * HW_ + h * W_ + w0 + wl) * 48 + 2 * d2) >> 1];
        const __hip_bfloat16* bp = (const __hip_bfloat16*)&u;
        t[wl * 1571 + c * 49 + 2 * d2]     = __bfloat162float(bp[0]);
        t[wl * 1571 + c * 49 + 2 * d2 + 1] = __bfloat162float(bp[1]);
    }
    __syncthreads();
    unsigned* actu = (unsigned*)act;
    #pragma unroll
    for (int k = 0; k < 24; ++k) {
        int f = tid + 256 * k;              // < 6144
        int cp = f % 16, wl = (f / 16) % 8, d = f / 128;
        union { unsigned u; __hip_bfloat16 hh[2]; } pk;
        pk.hh[0] = __float2bfloat16(t[wl * 1571 + (2 * cp) * 49 + d]);
        pk.hh[1] = __float2bfloat16(t[wl * 1571 + (2 * cp + 1) * 49 + d]);
        actu[(((size_t)h * 48 + d) * W_ + w0 + wl) * 16 + cp] = pk.u;
    }
}

// ---------------------------------------------------------------------------
// Conv 3x3x3 as implicit GEMM on MFMA 32x32x16 bf16 with d-blocking.
// One wave: 32 co x 32 w x 4 d outputs. Planes dd = d0-1..d0+4 each feed
// up to 3 MFMAs (kd sharing). acc[pi]: C/D col=lane&31 (w),
// row=(reg&3)+8*(reg>>2)+4*(lane>>5) (co).
// ---------------------------------------------------------------------------
__global__ __launch_bounds__(256) void conv_kernel(
    const __hip_bfloat16* __restrict__ act,   // [H][D][W][C]
    const short8* __restrict__ wrep,          // [27][2][64] short8
    const float* __restrict__ x,
    const float* __restrict__ g2, const float* __restrict__ b2,
    const float* __restrict__ m2, const float* __restrict__ v2,
    float* __restrict__ out)
{
    int lane = threadIdx.x & 63;
    int wid  = blockIdx.x * 4 + (threadIdx.x >> 6);   // 0..5375
    int wt = wid % 7;
    int t1 = wid / 7;
    int h  = t1 & 63;
    int d0 = (t1 >> 6) * 4;          // 0,4,...,44
    int w0 = wt * 32;
    int n   = lane & 31;
    int ci0 = (lane >> 5) * 8;

    float16v acc[4];
    #pragma unroll
    for (int i = 0; i < 4; ++i) acc[i] = (float16v)(0.0f);

    #pragma unroll
    for (int kh = 0; kh < 3; ++kh) {
        int hh = h + kh - 1;
        if (hh < 0 || hh >= H_) continue;                  // wave-uniform
        #pragma unroll
        for (int kw = 0; kw < 3; ++kw) {
            int ww = w0 + kw - 1 + n;
            bool wok = (ww >= 0 && ww < W_);
            int wwc = wok ? ww : 0;
            const __hip_bfloat16* pl = act + ((size_t)hh * D_ * W_ + wwc) * C_;
            #pragma unroll
            for (int cih = 0; cih < 2; ++cih) {
                short8 af[3];
                #pragma unroll
                for (int kd = 0; kd < 3; ++kd)
                    af[kd] = wrep[(((kd*3 + kh)*3 + kw)*2 + cih)*64 + lane];
                #pragma unroll
                for (int p = 0; p < 6; ++p) {
                    int dd = d0 - 1 + p;
                    if (dd < 0 || dd >= D_) continue;      // wave-uniform
                    short8 bf = {0,0,0,0,0,0,0,0};
                    if (wok)
                        bf = *(const short8*)(pl + (size_t)dd * W_ * C_ + cih*16 + ci0);
                    #pragma unroll
                    for (int kd = 0; kd < 3; ++kd) {
                        int pi = p - kd;
                        if (pi < 0 || pi > 3) continue;
                        acc[pi] = __builtin_amdgcn_mfma_f32_32x32x16_bf16(
                            af[kd], bf, acc[pi], 0, 0, 0);
                    }
                }
            }
        }
    }

    int wl = w0 + n;
    bool wvalid = wl < W_;
    int coh = 4 * (lane >> 5);
    #pragma unroll
    for (int r = 0; r < 16; ++r) {
        int co = (r & 3) + 8 * (r >> 2) + coh;
        float s2 = g2[co] * rsqrtf(v2[co] + EPS_);
        float o2 = b2[co] - m2[co] * s2;
        #pragma unroll
        for (int pi = 0; pi < 4; ++pi) {
            size_t idx = ((size_t)(co * D_ + d0 + pi) * H_ + h) * W_ + wl;
            if (wvalid)
                out[idx] = fmaxf(acc[pi][r] * s2 + o2 + x[idx], 0.0f);
        }
    }
}

// ---------------------------------------------------------------------------
extern "C" void kernel_launch(void* const* d_in, const int* in_sizes, int n_in,
                              void* d_out, int out_size, void* d_ws, size_t ws_size,
                              hipStream_t stream)
{
    const float* x    = (const float*)d_in[0];
    const float* g    = (const float*)d_in[1];
    const float* cw   = (const float*)d_in[2];
    const float* bn1g = (const float*)d_in[3];
    const float* bn1b = (const float*)d_in[4];
    const float* bn1m = (const float*)d_in[5];
    const float* bn1v = (const float*)d_in[6];
    const float* bn2g = (const float*)d_in[7];
    const float* bn2b = (const float*)d_in[8];
    const float* bn2m = (const float*)d_in[9];
    const float* bn2v = (const float*)d_in[10];
    float* out = (float*)d_out;

    char* ws = (char*)d_ws;
    float* wn  = (float*)ws;                                   // 1,064,960 B
    float* wnT = (float*)(ws + 1064960);                       //   532,480 B
    __hip_bfloat16* wrep = (__hip_bfloat16*)(ws + 1597440);    //    55,296 B
    __hip_bfloat16* d12t = (__hip_bfloat16*)(ws + 1652736);    // 40,894,464 B
    __hip_bfloat16* act  = (__hip_bfloat16*)(ws + 42547200);   // 40,894,464 B
    float* xt = out;   // d_out doubles as fp32 xt scratch; dead before conv

    prep_kernel<<<316, 256, 0, stream>>>(g, cw, wn, wnT, wrep);
    t0_kernel<<<1664, 256, 0, stream>>>(x, xt);
    sga_w_kernel<<<512, 256, 0, stream>>>(xt, wn, d12t);
    sga_h_kernel<<<1664, 256, 0, stream>>>(xt, wnT, d12t, bn1g, bn1b, bn1m, bn1v);
    trans_kernel<<<1664, 256, 0, stream>>>(d12t, act);
    conv_kernel<<<1344, 256, 0, stream>>>(act, (const short8*)wrep, x,
                                          bn2g, bn2b, bn2m, bn2v, out);
}

// Round 6
// 432.831 us; speedup vs baseline: 3.3237x; 1.0378x over previous
//
#include <hip/hip_runtime.h>
#include <hip/hip_bf16.h>
#include <cstddef>

#define C_ 32
#define D_ 48
#define H_ 64
#define W_ 208
#define HW_ 13312            // H_*W_
#define HS_ 9984             // W_*48, xt h-stride
#define EPS_ 1e-5f

typedef __attribute__((ext_vector_type(8))) short short8;
typedef __attribute__((ext_vector_type(4))) float float4v;
typedef __attribute__((ext_vector_type(16))) float float16v;

// ---------------------------------------------------------------------------
// DPP helpers (VALU-latency cross-lane; invalid lanes keep old = src)
// ---------------------------------------------------------------------------
template<int CTRL>
__device__ __forceinline__ float dppmov(float x) {
    int v = __builtin_bit_cast(int, x);
    return __builtin_bit_cast(float,
        __builtin_amdgcn_update_dpp(v, v, CTRL, 0xf, 0xf, false));
}
template<int CTRL>
__device__ __forceinline__ float dppmax(float m) {
    return fmaxf(m, dppmov<CTRL>(m));
}
__device__ __forceinline__ float rl(float v, int idx) {
    return __builtin_bit_cast(float,
        __builtin_amdgcn_readlane(__builtin_bit_cast(int, v), idx));
}

// One SGA recurrence step, all cross-lane via DPP (lane = d).
__device__ __forceinline__ float sga_step_dpp(float A, float xi,
    float w0, float w1, float w2, float w3, float w4, bool actv, bool ge47)
{
    float up = dppmov<0x138>(A);             // wave_shr:1, lane0 keeps A (d=0 clamp)
    float dn = dppmov<0x130>(A);             // wave_shl:1
    dn = ge47 ? A : dn;                      // d=47 clamp
    float m = actv ? A : -3.4e38f;
    m = dppmax<0x111>(m);
    m = dppmax<0x112>(m);
    m = dppmax<0x114>(m);
    m = dppmax<0x118>(m);
    m = dppmax<0x142>(m);
    m = dppmax<0x143>(m);
    float mall = rl(m, 63);
    return (w0*xi + w1*A) + ((w2*up + w3*dn) + w4*mall);
}

// ---------------------------------------------------------------------------
// Prep: L1-normalize guidance; transpose H-scan weights to [dd][i][w][h];
// repack conv weights into 32x32x16 MFMA A-frag layout.
// ---------------------------------------------------------------------------
__global__ __launch_bounds__(256) void prep_kernel(
    const float* __restrict__ g, const float* __restrict__ cw,
    float* __restrict__ wn, float* __restrict__ wnT,
    __hip_bfloat16* __restrict__ wrep)
{
    int idx = blockIdx.x * 256 + threadIdx.x;
    if (idx < 4 * HW_) {
        int dir = idx / HW_;
        int hw  = idx % HW_;
        const float* gb = g + dir * 5 * HW_ + hw;
        float v0 = gb[0*HW_], v1 = gb[1*HW_], v2 = gb[2*HW_], v3 = gb[3*HW_], v4 = gb[4*HW_];
        float s = fabsf(v0)+fabsf(v1)+fabsf(v2)+fabsf(v3)+fabsf(v4);
        float inv = 1.0f / fmaxf(s, 1e-12f);
        v0 *= inv; v1 *= inv; v2 *= inv; v3 *= inv; v4 *= inv;
        float* ob = wn + dir * 5 * HW_ + hw;
        ob[0*HW_] = v0; ob[1*HW_] = v1; ob[2*HW_] = v2; ob[3*HW_] = v3; ob[4*HW_] = v4;
        if (dir >= 2) {   // H-scan dirs: also write [dd][i][w][h]
            int hq = hw / W_, wq = hw % W_;
            float* oT = wnT + ((size_t)((dir-2)*5)*W_ + wq)*H_ + hq;
            oT[0]       = v0; oT[1*HW_] = v1; oT[2*HW_] = v2;
            oT[3*HW_]   = v3; oT[4*HW_] = v4;   // i-stride = W_*H_ = HW_
        }
    } else {
        int j = idx - 4 * HW_;
        if (j < 27 * 2 * 64 * 8) {
            int e    = j & 7;
            int lane = (j >> 3) & 63;
            int q    = j >> 9;            // 0..53
            int cih  = q & 1;
            int tap  = q >> 1;
            int co = lane & 31;
            int ci = cih * 16 + (lane >> 5) * 8 + e;
            wrep[j] = __float2bfloat16(cw[(co * C_ + ci) * 27 + tap]);
        }
    }
}

// ---------------------------------------------------------------------------
// t0: transpose x [c][d][h][w] fp32 -> xt [c][h][w][d] bf16 (lives in d_out)
// ---------------------------------------------------------------------------
__global__ __launch_bounds__(256) void t0_kernel(
    const float* __restrict__ x, __hip_bfloat16* __restrict__ xt)
{
    __shared__ float t[48 * 257];
    int tid = threadIdx.x;
    int c  = blockIdx.x / 52;
    int q0 = (blockIdx.x % 52) * 256;
    #pragma unroll
    for (int dd = 0; dd < 48; ++dd)
        t[dd * 257 + tid] = x[((size_t)c * 48 + dd) * HW_ + q0 + tid];
    __syncthreads();
    unsigned* xtu = (unsigned*)xt;
    #pragma unroll
    for (int k = 0; k < 24; ++k) {
        int f = tid + 256 * k;              // < 6144 bf16-pairs
        int d2 = f % 24, hwl = f / 24;
        union { unsigned u; __hip_bfloat16 hh[2]; } pk;
        pk.hh[0] = __float2bfloat16(t[(2 * d2) * 257 + hwl]);
        pk.hh[1] = __float2bfloat16(t[(2 * d2 + 1) * 257 + hwl]);
        xtu[(((size_t)c * HW_ + q0 + hwl) * 48 + 2 * d2) >> 1] = pk.u;
    }
}

// ---------------------------------------------------------------------------
// Register-chunked scan helpers over the bf16 d-innermost layout.
// ---------------------------------------------------------------------------
template<int LN>
__device__ __forceinline__ float chunk_fwd(float A,
    const __hip_bfloat16* __restrict__ xp, __hip_bfloat16* __restrict__ dp,
    const float* __restrict__ wb, int P0, int lane, bool actv, bool ge47)
{
    float xr[LN];
    #pragma unroll
    for (int j = 0; j < LN; ++j) xr[j] = __bfloat162float(xp[(size_t)(P0 + j) * 48]);
    int lm = lane & (LN - 1);
    float wv0 = wb[0*HW_ + P0 + lm], wv1 = wb[1*HW_ + P0 + lm],
          wv2 = wb[2*HW_ + P0 + lm], wv3 = wb[3*HW_ + P0 + lm],
          wv4 = wb[4*HW_ + P0 + lm];
    #pragma unroll
    for (int j = 0; j < LN; ++j) {
        A = sga_step_dpp(A, xr[j], rl(wv0,j), rl(wv1,j), rl(wv2,j),
                         rl(wv3,j), rl(wv4,j), actv, ge47);
        if (actv) dp[(size_t)(P0 + j) * 48] = __float2bfloat16(A);
    }
    return A;
}

template<int LN>
__device__ __forceinline__ float chunk_rev(float A,
    const __hip_bfloat16* __restrict__ xp, __hip_bfloat16* __restrict__ dp,
    const float* __restrict__ wb, int P0, int lane, bool actv, bool ge47)
{
    float xr[LN]; __hip_bfloat16 dr[LN];
    #pragma unroll
    for (int j = 0; j < LN; ++j) {
        xr[j] = __bfloat162float(xp[(size_t)(P0 + j) * 48]);
        dr[j] = dp[(size_t)(P0 + j) * 48];
    }
    int lm = lane & (LN - 1);
    float wv0 = wb[0*HW_ + P0 + lm], wv1 = wb[1*HW_ + P0 + lm],
          wv2 = wb[2*HW_ + P0 + lm], wv3 = wb[3*HW_ + P0 + lm],
          wv4 = wb[4*HW_ + P0 + lm];
    #pragma unroll
    for (int j = LN - 1; j >= 0; --j) {
        A = sga_step_dpp(A, xr[j], rl(wv0,j), rl(wv1,j), rl(wv2,j),
                         rl(wv3,j), rl(wv4,j), actv, ge47);
        if (actv)
            dp[(size_t)(P0 + j) * 48] =
                __float2bfloat16(fmaxf(__bfloat162float(dr[j]), A));
    }
    return A;
}

// ---------------------------------------------------------------------------
// Horizontal scans: 2048 independent waves (c,h). No LDS, no barriers.
// ---------------------------------------------------------------------------
__global__ __launch_bounds__(256) void sga_w_kernel(
    const __hip_bfloat16* __restrict__ xt, const float* __restrict__ wn,
    __hip_bfloat16* __restrict__ d12)
{
    int lane = threadIdx.x & 63;
    int wid  = blockIdx.x * 4 + (threadIdx.x >> 6);   // 0..2047
    int c = wid >> 6, h = wid & 63;
    int d = lane < 48 ? lane : 47;
    bool actv = lane < 48, ge47 = lane >= 47;
    const __hip_bfloat16* xp = xt + ((size_t)c * HW_ + h * W_) * 48 + d;
    __hip_bfloat16* dp = d12 + ((size_t)c * HW_ + h * W_) * 48 + d;
    const float* w1 = wn + (size_t)0 * 5 * HW_ + h * W_;
    const float* w2 = wn + (size_t)1 * 5 * HW_ + h * W_;

    float A = __bfloat162float(xp[0]);
    for (int cc = 0; cc < 6; ++cc)
        A = chunk_fwd<32>(A, xp, dp, w1, cc * 32, lane, actv, ge47);
    A = chunk_fwd<16>(A, xp, dp, w1, 192, lane, actv, ge47);

    A = __bfloat162float(xp[(size_t)207 * 48]);
    A = chunk_rev<16>(A, xp, dp, w2, 192, lane, actv, ge47);
    for (int cc = 0; cc < 6; ++cc)
        A = chunk_rev<32>(A, xp, dp, w2, 160 - cc * 32, lane, actv, ge47);
}

// ---------------------------------------------------------------------------
// Vertical scans: 6656 independent waves (c,w).
// ---------------------------------------------------------------------------
__global__ __launch_bounds__(256) void sga_h_kernel(
    const __hip_bfloat16* __restrict__ xt, const float* __restrict__ wnT,
    __hip_bfloat16* __restrict__ d12,
    const float* __restrict__ g1, const float* __restrict__ b1,
    const float* __restrict__ m1, const float* __restrict__ v1)
{
    int lane = threadIdx.x & 63;
    int wid  = blockIdx.x * 4 + (threadIdx.x >> 6);   // 0..6655
    int c = wid / W_, w = wid % W_;
    int d = lane < 48 ? lane : 47;
    bool actv = lane < 48, ge47 = lane >= 47;
    const __hip_bfloat16* xp = xt + ((size_t)c * HW_ + w) * 48 + d;  // + h*HS_
    __hip_bfloat16* dp = d12 + ((size_t)c * HW_ + w) * 48 + d;
    const float* w3 = wnT + ((size_t)0 * W_ + w) * H_;               // + i*HW_ + h
    const float* w4 = wnT + ((size_t)5 * W_ + w) * H_;

    float s1 = g1[c] * rsqrtf(v1[c] + EPS_);
    float o1 = b1[c] - m1[c] * s1;

    float d3v[64];
    float A = __bfloat162float(xp[0]);
    #pragma unroll
    for (int cc = 0; cc < 4; ++cc) {
        int h0 = cc * 16;
        float xr[16];
        #pragma unroll
        for (int j = 0; j < 16; ++j)
            xr[j] = __bfloat162float(xp[(size_t)(h0 + j) * HS_]);
        int lm = lane & 15;
        float wv0 = w3[0*HW_ + h0 + lm], wv1 = w3[1*HW_ + h0 + lm],
              wv2 = w3[2*HW_ + h0 + lm], wv3 = w3[3*HW_ + h0 + lm],
              wv4 = w3[4*HW_ + h0 + lm];
        #pragma unroll
        for (int j = 0; j < 16; ++j) {
            A = sga_step_dpp(A, xr[j], rl(wv0,j), rl(wv1,j), rl(wv2,j),
                             rl(wv3,j), rl(wv4,j), actv, ge47);
            d3v[h0 + j] = A;
        }
    }
    A = __bfloat162float(xp[(size_t)63 * HS_]);
    #pragma unroll
    for (int cc = 0; cc < 4; ++cc) {
        int h0 = 48 - cc * 16;
        float xr[16]; __hip_bfloat16 dr[16];
        #pragma unroll
        for (int j = 0; j < 16; ++j) {
            xr[j] = __bfloat162float(xp[(size_t)(h0 + j) * HS_]);
            dr[j] = dp[(size_t)(h0 + j) * HS_];
        }
        int lm = lane & 15;
        float wv0 = w4[0*HW_ + h0 + lm], wv1 = w4[1*HW_ + h0 + lm],
              wv2 = w4[2*HW_ + h0 + lm], wv3 = w4[3*HW_ + h0 + lm],
              wv4 = w4[4*HW_ + h0 + lm];
        #pragma unroll
        for (int j = 15; j >= 0; --j) {
            A = sga_step_dpp(A, xr[j], rl(wv0,j), rl(wv1,j), rl(wv2,j),
                             rl(wv3,j), rl(wv4,j), actv, ge47);
            if (actv) {
                float comb = fmaxf(fmaxf(d3v[h0 + j], A), __bfloat162float(dr[j]));
                dp[(size_t)(h0 + j) * HS_] =
                    __float2bfloat16(fmaxf(comb * s1 + o1, 0.0f));
            }
        }
    }
}

// ---------------------------------------------------------------------------
// trans: st bf16 [c][h][w][d] -> act bf16 [h][d][w][c] (LDS tiled)
// ---------------------------------------------------------------------------
__global__ __launch_bounds__(256) void trans_kernel(
    const __hip_bfloat16* __restrict__ st, __hip_bfloat16* __restrict__ act)
{
    __shared__ float t[8 * 1571];   // addr = wl*1571 + c*49 + d
    int tid = threadIdx.x;
    int h  = blockIdx.x / 26;
    int w0 = (blockIdx.x % 26) * 8;
    const unsigned* stu = (const unsigned*)st;
    #pragma unroll
    for (int k = 0; k < 24; ++k) {
        int f = tid + 256 * k;              // < 6144
        int d2 = f % 24, wl = (f / 24) % 8, c = f / 192;
        unsigned u = stu[(((size_t)c * HW_ + h * W_ + w0 + wl) * 48 + 2 * d2) >> 1];
        const __hip_bfloat16* bp = (const __hip_bfloat16*)&u;
        t[wl * 1571 + c * 49 + 2 * d2]     = __bfloat162float(bp[0]);
        t[wl * 1571 + c * 49 + 2 * d2 + 1] = __bfloat162float(bp[1]);
    }
    __syncthreads();
    unsigned* actu = (unsigned*)act;
    #pragma unroll
    for (int k = 0; k < 24; ++k) {
        int f = tid + 256 * k;              // < 6144
        int cp = f % 16, wl = (f / 16) % 8, d = f / 128;
        union { unsigned u; __hip_bfloat16 hh[2]; } pk;
        pk.hh[0] = __float2bfloat16(t[wl * 1571 + (2 * cp) * 49 + d]);
        pk.hh[1] = __float2bfloat16(t[wl * 1571 + (2 * cp + 1) * 49 + d]);
        actu[(((size_t)h * 48 + d) * W_ + w0 + wl) * 16 + cp] = pk.u;
    }
}

// ---------------------------------------------------------------------------
// Conv 3x3x3 as implicit GEMM on MFMA 32x32x16 bf16, 2 d-planes per wave.
// One wave: 32 co x 32 w x 2 d outputs (acc = 32 regs). Loads guarded,
// MFMAs unconditional (zero B-frag is a no-op). launch_bounds(256,4)
// caps VGPR at 128 -> 4 waves/SIMD residency.
// ---------------------------------------------------------------------------
__global__ __launch_bounds__(256, 4) void conv_kernel(
    const __hip_bfloat16* __restrict__ act,   // [H][D][W][C]
    const short8* __restrict__ wrep,          // [27][2][64] short8
    const float* __restrict__ x,
    const float* __restrict__ g2, const float* __restrict__ b2,
    const float* __restrict__ m2, const float* __restrict__ v2,
    float* __restrict__ out)
{
    int lane = threadIdx.x & 63;
    int wid  = blockIdx.x * 4 + (threadIdx.x >> 6);   // 0..10751
    int wt = wid % 7;
    int t1 = wid / 7;
    int h  = t1 & 63;
    int d0 = (t1 >> 6) * 2;          // 0,2,...,46
    int w0 = wt * 32;
    int n   = lane & 31;
    int ci0 = (lane >> 5) * 8;

    float16v acc0 = (float16v)(0.0f);
    float16v acc1 = (float16v)(0.0f);

    #pragma unroll
    for (int kh = 0; kh < 3; ++kh) {
        int hh = h + kh - 1;
        if (hh < 0 || hh >= H_) continue;                  // wave-uniform
        #pragma unroll
        for (int kw = 0; kw < 3; ++kw) {
            int ww = w0 + kw - 1 + n;
            bool wok = (ww >= 0 && ww < W_);
            int wwc = wok ? ww : 0;
            const __hip_bfloat16* pl =
                act + ((size_t)hh * D_ * W_ + wwc) * C_ + ci0;
            #pragma unroll
            for (int cih = 0; cih < 2; ++cih) {
                const __hip_bfloat16* pc = pl + cih * 16;
                short8 af[3];
                #pragma unroll
                for (int kd = 0; kd < 3; ++kd)
                    af[kd] = wrep[(((kd*3 + kh)*3 + kw)*2 + cih)*64 + lane];
                short8 bf[4];
                #pragma unroll
                for (int p = 0; p < 4; ++p) {
                    int dd = d0 - 1 + p;
                    short8 z = {0,0,0,0,0,0,0,0};
                    bf[p] = z;
                    if (wok && dd >= 0 && dd < D_)
                        bf[p] = *(const short8*)(pc + (size_t)dd * W_ * C_);
                }
                // plane p feeds acc[p-kd] via tap kd
                acc0 = __builtin_amdgcn_mfma_f32_32x32x16_bf16(af[0], bf[0], acc0, 0, 0, 0);
                acc1 = __builtin_amdgcn_mfma_f32_32x32x16_bf16(af[0], bf[1], acc1, 0, 0, 0);
                acc0 = __builtin_amdgcn_mfma_f32_32x32x16_bf16(af[1], bf[1], acc0, 0, 0, 0);
                acc1 = __builtin_amdgcn_mfma_f32_32x32x16_bf16(af[1], bf[2], acc1, 0, 0, 0);
                acc0 = __builtin_amdgcn_mfma_f32_32x32x16_bf16(af[2], bf[2], acc0, 0, 0, 0);
                acc1 = __builtin_amdgcn_mfma_f32_32x32x16_bf16(af[2], bf[3], acc1, 0, 0, 0);
            }
        }
    }

    int wl = w0 + n;
    bool wvalid = wl < W_;
    int coh = 4 * (lane >> 5);
    #pragma unroll
    for (int r = 0; r < 16; ++r) {
        int co = (r & 3) + 8 * (r >> 2) + coh;
        float s2 = g2[co] * rsqrtf(v2[co] + EPS_);
        float o2 = b2[co] - m2[co] * s2;
        size_t idx0 = ((size_t)(co * D_ + d0) * H_ + h) * W_ + wl;
        if (wvalid) {
            out[idx0]       = fmaxf(acc0[r] * s2 + o2 + x[idx0], 0.0f);
            out[idx0 + HW_] = fmaxf(acc1[r] * s2 + o2 + x[idx0 + HW_], 0.0f);
        }
    }
}

// ---------------------------------------------------------------------------
extern "C" void kernel_launch(void* const* d_in, const int* in_sizes, int n_in,
                              void* d_out, int out_size, void* d_ws, size_t ws_size,
                              hipStream_t stream)
{
    const float* x    = (const float*)d_in[0];
    const float* g    = (const float*)d_in[1];
    const float* cw   = (const float*)d_in[2];
    const float* bn1g = (const float*)d_in[3];
    const float* bn1b = (const float*)d_in[4];
    const float* bn1m = (const float*)d_in[5];
    const float* bn1v = (const float*)d_in[6];
    const float* bn2g = (const float*)d_in[7];
    const float* bn2b = (const float*)d_in[8];
    const float* bn2m = (const float*)d_in[9];
    const float* bn2v = (const float*)d_in[10];
    float* out = (float*)d_out;

    char* ws = (char*)d_ws;
    float* wn  = (float*)ws;                                   // 1,064,960 B
    float* wnT = (float*)(ws + 1064960);                       //   532,480 B
    __hip_bfloat16* wrep = (__hip_bfloat16*)(ws + 1597440);    //    55,296 B
    __hip_bfloat16* d12t = (__hip_bfloat16*)(ws + 1652736);    // 40,894,464 B
    __hip_bfloat16* act  = (__hip_bfloat16*)(ws + 42547200);   // 40,894,464 B
    __hip_bfloat16* xt = (__hip_bfloat16*)out;  // d_out as bf16 xt scratch

    prep_kernel<<<316, 256, 0, stream>>>(g, cw, wn, wnT, wrep);
    t0_kernel<<<1664, 256, 0, stream>>>(x, xt);
    sga_w_kernel<<<512, 256, 0, stream>>>(xt, wn, d12t);
    sga_h_kernel<<<1664, 256, 0, stream>>>(xt, wnT, d12t, bn1g, bn1b, bn1m, bn1v);
    trans_kernel<<<1664, 256, 0, stream>>>(d12t, act);
    conv_kernel<<<2688, 256, 0, stream>>>(act, (const short8*)wrep, x,
                                          bn2g, bn2b, bn2m, bn2v, out);
}